// Round 13
// baseline (317.949 us; speedup 1.0000x reference)
//
#include <hip/hip_runtime.h>
#include <math.h>

// Problem dims
#define D 256
#define NEF 8192        // feature codebook
#define NEC 1024        // class codebook

// Output layout (flat float32): loss | quantized[257*64*3*256] | f_perp | c_perp | idx[257*64*3]
#define OUT_QBASE   1
#define OUT_FPERP   12632065
#define OUT_CPERP   12632066
#define OUT_IDXBASE 12632067

// Scratch inside the quantized output region (rewritten by vq_gather later;
// fmerge completes before gather launches -> no overlap race). Float offsets.
// 8 partitions x 8 candidates per row (R13/R14-verified layout) + u16 norms.
#define F_SC  0           // feature rescored scores [16384 row][8 part][8]
#define F_IX  1048576     // feature candidate codebook idx (int view)
#define C_SC  2097152     // class   rescored scores [64 row][8 part][8]
#define C_IX  2101248
#define EBF_F 2105347     // bf16 feature codebook, row-major (byte addr %16==0)
#define EBF_C 3153923     // bf16 class codebook (ends 3285123)
#define E2HF  3285123     // u16 biased e2, feature (4096 float slots; byte%16==0)
#define E2HC  3289219     // u16 biased e2, class (512 float slots; byte%16==0)

// Workspace layout (bytes)
#define WS_CNTF  0        // 8192 int
#define WS_CNTC  32768    // 1024 int
#define WS_LOSS  36864    // float[2]: loss_c, loss_f
#define WS_E2F   49152    // 8192 float
#define WS_E2C   81920    // 1024 float

typedef short bf8 __attribute__((ext_vector_type(8)));     // 8 bf16 (4 VGPRs)
typedef float f32x4 __attribute__((ext_vector_type(4)));   // MFMA C/D frag

// float -> bf16 bits, round-to-nearest-even (coarse pass only)
__device__ __forceinline__ unsigned f2bf(float f) {
    union { float f; unsigned u; } v; v.f = f;
    return (v.u + 0x7FFFu + ((v.u >> 16) & 1u)) >> 16;
}

// async global(16B/lane) -> LDS (linear, wave-uniform base + lane*16)
__device__ __forceinline__ void gload_lds16(const void* g, void* l) {
    __builtin_amdgcn_global_load_lds(
        (const __attribute__((address_space(1))) void*)g,
        (__attribute__((address_space(3))) void*)l, 16, 0, 0);
}

// single-instruction u32 median-of-3 (gfx9+ V_MED3_U32)
#define MED3U(d, a, b_, c_) \
    asm("v_med3_u32 %0, %1, %2, %3" : "=v"(d) : "v"(a), "v"(b_), "v"(c_))

// Lexicographic (score, idx) insert — EXACT-path only (fmerge). Matches
// jax.lax.top_k stable tie-breaking.
__device__ __forceinline__ void insert3(float s, int idx, float* bs, int* bi) {
    bool lt2 = (s < bs[2]) || (s == bs[2] && idx < bi[2]);
    if (lt2) {
        bool lt1 = (s < bs[1]) || (s == bs[1] && idx < bi[1]);
        if (lt1) {
            bs[2] = bs[1]; bi[2] = bi[1];
            bool lt0 = (s < bs[0]) || (s == bs[0] && idx < bi[0]);
            if (lt0) { bs[1] = bs[0]; bi[1] = bi[0]; bs[0] = s; bi[0] = idx; }
            else     { bs[1] = s;     bi[1] = idx; }
        } else       { bs[2] = s;     bi[2] = idx; }
    }
}

// Coarse packed-u32 top-8 insert (merge phase)
__device__ __forceinline__ void ins8(unsigned p, unsigned* h) {
    if (p < h[7]) {
        h[7] = p;
#pragma unroll
        for (int q = 7; q > 0; --q)
            if (h[q] < h[q - 1]) { unsigned t = h[q]; h[q] = h[q - 1]; h[q - 1] = t; }
    }
}

// ---- fused: codebook norms + fp32->bf16 convert + workspace zeroing.
// Also emits u16 fixed-point biased norms (e2+1024)*32 for the coarse pass
// (error <= 0.016, 8x finer than the 0.125 coarse pack truncation).
__global__ __launch_bounds__(256)
void vq_prep(const float* __restrict__ femb, const float* __restrict__ cemb,
             unsigned short* __restrict__ ebf_f, unsigned short* __restrict__ ebf_c,
             float* __restrict__ e2f, float* __restrict__ e2c,
             unsigned short* __restrict__ e2h_f, unsigned short* __restrict__ e2h_c,
             int* __restrict__ counts_f, int* __restrict__ counts_c,
             float* __restrict__ loss)
{
    int zid = blockIdx.x * 256 + threadIdx.x;
    if (zid < 8192)      counts_f[zid] = 0;
    else if (zid < 9216) counts_c[zid - 8192] = 0;
    else if (zid < 9218) loss[zid - 9216] = 0.f;

    int wave = blockIdx.x * 4 + (threadIdx.x >> 6);
    int lane = threadIdx.x & 63;
    const float* src; unsigned short* dst; float* ndst; unsigned short* nh;
    if (wave < NEF) { src = femb + (size_t)wave * D; dst = ebf_f + (size_t)wave * D; ndst = e2f + wave; nh = e2h_f + wave; }
    else { int w2 = wave - NEF; src = cemb + (size_t)w2 * D; dst = ebf_c + (size_t)w2 * D; ndst = e2c + w2; nh = e2h_c + w2; }
    float4 v = *(const float4*)(src + lane * 4);
    uint2 o;
    o.x = f2bf(v.x) | (f2bf(v.y) << 16);
    o.y = f2bf(v.z) | (f2bf(v.w) << 16);
    *(uint2*)(dst + lane * 4) = o;
    float s = v.x * v.x + v.y * v.y + v.z * v.z + v.w * v.w;
#pragma unroll
    for (int off = 32; off > 0; off >>= 1) s += __shfl_down(s, off);
    if (lane == 0) {
        *ndst = s;
        *nh = (unsigned short)__float2int_rn((s + 1024.f) * 32.f);
    }
}

// ---- coarse pass, R17 structure: R16 schedule at 64 rows/wave.
// Block = 256 rows x 1024-emb partition (8 partitions, pt=blk&7 -> XCD
// round-robin), 4 waves x 64 rows. A (64x256 bf16, 128 VGPR) in regs.
// B streamed per 32-emb chunk (16KB) via global_load_lds w16 into a 3-deep
// ring (48KB), depth-2 prefetch, RAW s_barrier + counted s_waitcnt vmcnt(4)
// (R16-verified). Per wave per chunk: 16 swizzled ds_read_b128 feed 64
// MFMAs (4:1 — the R16->R17 lever: per-CU LDS-pipe work and barrier count
// both halve at constant waves/CU). e2 u16 biased in LDS (2KB). LDS 56KB
// (overlay dump[256][48]+topix needs it) -> 2 blocks/CU; grid 520 = 512
// feature (2/CU exact, single round, no tail) + 8 class.
__global__ __launch_bounds__(256, 2)
void vq_coarse(const float* __restrict__ features,
               const unsigned short* __restrict__ ebf_f,
               const unsigned short* __restrict__ ebf_c,
               const float* __restrict__ femb, const float* __restrict__ cemb,
               const float* __restrict__ e2f, const float* __restrict__ e2c,
               const unsigned short* __restrict__ e2h_f,
               const unsigned short* __restrict__ e2h_c,
               float* __restrict__ out)
{
    __shared__ uint4 sm[3584];   // 56KB: B ring buf0..2 [0,48KB), e2u16 [48KB,50KB)
                                 // post-loop overlay: dump[256][48] [0,48KB) + topix [48KB,56KB)
    const int tid = threadIdx.x, lane = tid & 63, w = tid >> 6;
    const int l15 = lane & 15, q4 = lane >> 4;
    const int blk = blockIdx.x;
    const bool is_class = blk >= 512;

    const float* xbase;            // block's first row (fp32 features)
    const char* ebase8;            // partition base in bf16 codebook (bytes)
    const unsigned short* e2hp;    // partition u16 biased norms
    const float* cb; const float* e2full;
    int nch, eoff, nrows_blk, npart;
    if (is_class) {
        int p = blk - 512;
        xbase = features;                      // class rows 0..63
        eoff = p * 128; nch = 4; nrows_blk = 64; npart = 128;
        ebase8 = (const char*)(ebf_c + (size_t)eoff * D);
        e2hp = e2h_c + eoff; cb = cemb; e2full = e2c;
    } else {
        int rb = blk >> 3, pt = blk & 7;
        xbase = features + (size_t)(64 + rb * 256) * D;
        eoff = pt * 1024; nch = 32; nrows_blk = 256; npart = 1024;
        ebase8 = (const char*)(ebf_f + (size_t)eoff * D);
        e2hp = e2h_f + eoff; cb = femb; e2full = e2f;
    }

    // class blocks: only wave 0 carries rows (64); waves 1-3 stage+barrier only
    const bool active = !is_class || (w == 0);

    // ---- staging constants (R7/R16-verified swizzle, 16KB chunk = 4 loads/thr).
    // LDS linear byte L = ring + tid*16 + p*4096 holds chunk byte (L ^ xv),
    // xv = ((L>>9)&7)<<4 = ((tid>>5)&7)<<4 (p*4096, ring*16384 are 0 mod 8
    // in L>>9). Reader applies the same XOR.
    const unsigned xv = ((unsigned)(tid >> 5) & 7u) << 4;
    unsigned soff[4];
#pragma unroll
    for (int p = 0; p < 4; ++p)
        soff[p] = ((unsigned)(tid * 16 + p * 4096)) ^ xv;
    char* const lwb = (char*)sm + (size_t)w * 1024;   // wave's linear LDS base

#define STAGE(C, B_) {                                                          \
    const char* cb8_ = ebase8 + (size_t)(C) * 16384;                            \
    char* lb_ = lwb + (B_) * 16384;                                             \
    _Pragma("unroll")                                                           \
    for (int p = 0; p < 4; ++p)                                                 \
        gload_lds16(cb8_ + soff[p], lb_ + p * 4096);                            \
}

    // per-lane swizzled B-frag read offset pieces: logical
    // P = (j*16+l15)*512 + s*64 + q4*16, read addr = P ^ ((l15&7)<<4)
    const unsigned rq = ((unsigned)(q4 * 16)) ^ (((unsigned)(l15 & 7)) << 4);
    const unsigned lrow = (unsigned)l15 * 512;

    unsigned short* const e2s16 = (unsigned short*)((char*)sm + 49152);  // u16 biased

    unsigned t3[4][4][3];
#pragma unroll
    for (int i = 0; i < 4; ++i)
#pragma unroll
        for (int r = 0; r < 4; ++r)
#pragma unroll
            for (int s3 = 0; s3 < 3; ++s3) t3[i][r][s3] = 0xFFFFFFFFu;

    // ---- prologue: u16 e2 partition -> LDS; A frags -> regs (verified
    // pattern: lane holds X[row = w*64 + i*16 + l15][k = s*32 + q4*8 .. +8]).
    // The one-time __syncthreads drains these loads so the main loop's vmcnt
    // queue contains ONLY stage loads (counted waits stay exact).
    for (int i4 = tid; i4 < (npart >> 3); i4 += 256)
        ((uint4*)e2s16)[i4] = ((const uint4*)e2hp)[i4];
    bf8 A[4][8];
    if (active) {
        const float* xw = xbase + (size_t)(w * 64 + l15) * D + q4 * 8;
#pragma unroll
        for (int i = 0; i < 4; ++i)
#pragma unroll
            for (int s = 0; s < 8; ++s) {
                const float* p = xw + i * 16 * D + s * 32;
                float4 a = *(const float4*)p;
                float4 b = *(const float4*)(p + 4);
                uint4 o;
                o.x = f2bf(a.x) | (f2bf(a.y) << 16);
                o.y = f2bf(a.z) | (f2bf(a.w) << 16);
                o.z = f2bf(b.x) | (f2bf(b.y) << 16);
                o.w = f2bf(b.z) | (f2bf(b.w) << 16);
                A[i][s] = *(bf8*)&o;
            }
    }
    __syncthreads();   // e2 visible; A/e2 loads drained

    // e2 rotation regs for chunk 0 (LDS u16 -> biased float)
    float e2c0 = (float)e2s16[l15] * 0.03125f;
    float e2c1 = (float)e2s16[16 + l15] * 0.03125f;

    // depth-2 prefetch: chunks 0,1 into ring 0,1
    STAGE(0, 0)
    STAGE(1, 1)

    // ---- main loop: one RAW barrier per 32-emb chunk, counted vmcnt.
    // At iter c the queue holds (oldest-first) chunks c, c+1 (4 loads each);
    // vmcnt(4) retires exactly chunk c. STAGE(c+2) reuses the ring slot last
    // read at iter c-1 — all waves passed that compute before this barrier.
#pragma unroll 1
    for (int c = 0; c < nch; ++c) {
        const int rem = nch - 1 - c;
        if (rem >= 1) asm volatile("s_waitcnt vmcnt(4)" ::: "memory");
        else          asm volatile("s_waitcnt vmcnt(0)" ::: "memory");
        __builtin_amdgcn_s_barrier();
        asm volatile("" ::: "memory");
        if (c + 2 < nch) STAGE(c + 2, (c + 2) % 3)
        if (active) {
            // prefetch next chunk's e2 pair (consumed next iteration; the
            // ds_read latency hides under this chunk's MFMAs)
            float e2n0 = 0.f, e2n1 = 0.f;
            if (c + 1 < nch) {
                e2n0 = (float)e2s16[(c + 1) * 32 + l15] * 0.03125f;
                e2n1 = (float)e2s16[(c + 1) * 32 + 16 + l15] * 0.03125f;
            }
            const char* bb = (const char*)sm + (c % 3) * 16384;
            f32x4 acc[4][2];
#pragma unroll
            for (int i = 0; i < 4; ++i)
#pragma unroll
                for (int j = 0; j < 2; ++j) acc[i][j] = (f32x4){0.f, 0.f, 0.f, 0.f};
            __builtin_amdgcn_s_setprio(1);
#pragma unroll
            for (int s = 0; s < 8; ++s) {
                const char* ba = bb + lrow + (rq ^ (unsigned)(s << 6));
                bf8 bv0 = *(const bf8*)(ba);
                bf8 bv1 = *(const bf8*)(ba + 8192);
#pragma unroll
                for (int i = 0; i < 4; ++i) {
                    acc[i][0] = __builtin_amdgcn_mfma_f32_16x16x32_bf16(A[i][s], bv0, acc[i][0], 0, 0, 0);
                    acc[i][1] = __builtin_amdgcn_mfma_f32_16x16x32_bf16(A[i][s], bv1, acc[i][1], 0, 0, 0);
                }
            }
            __builtin_amdgcn_s_setprio(0);
            // fold chunk scores into per-lane packed top-3.
            // 6 ops/score: fmaf, and_or pack (positive-monotone bits, bias
            // guarantees sc>0), min/med3/max/min. 10-bit idx, 22-bit score.
#pragma unroll
            for (int j = 0; j < 2; ++j) {
                const float e2v = j ? e2c1 : e2c0;
                const unsigned elb = (unsigned)(c * 32 + j * 16 + l15);
#pragma unroll
                for (int i = 0; i < 4; ++i)
#pragma unroll
                    for (int r = 0; r < 4; ++r) {
                        float sc = fmaf(-2.f, acc[i][j][r], e2v);
                        unsigned u = __float_as_uint(sc);
                        unsigned p = (u & 0xFFFFFC00u) | elb;
                        unsigned* b = t3[i][r];
                        unsigned n0 = p < b[0] ? p : b[0];
                        unsigned n1; MED3U(n1, p, b[0], b[1]);
                        unsigned x1 = p > b[1] ? p : b[1];
                        unsigned n2 = x1 < b[2] ? x1 : b[2];
                        b[0] = n0; b[1] = n1; b[2] = n2;
                    }
            }
            e2c0 = e2n0; e2c1 = e2n1;
        }
    }
    __syncthreads();   // all reads done; vmcnt already 0 — safe to overlay

    // ---- dump per-lane packed top-3 -> LDS overlay (stride 48 u32;
    // serial 48-word reads at odd... stride 48: lanes t,t+2 alias 2-way = free)
    unsigned* dump = (unsigned*)sm;                        // [256][48]
    int* topix = (int*)((char*)sm + 49152);                // [256][8]
    if (active) {
#pragma unroll
        for (int i = 0; i < 4; ++i)
#pragma unroll
            for (int r = 0; r < 4; ++r) {
                int row = w * 64 + i * 16 + q4 * 4 + r;  // C layout: row=q4*4+reg
#pragma unroll
                for (int s3 = 0; s3 < 3; ++s3)
                    dump[row * 48 + l15 * 3 + s3] = t3[i][r][s3];
            }
    }
    __syncthreads();

    // ---- per-row merge: 16 lanes x top-3 (48 cands) -> coarse top-8
    if (tid < nrows_blk) {
        unsigned h[8];
#pragma unroll
        for (int q = 0; q < 8; ++q) h[q] = 0xFFFFFFFFu;
        const unsigned* src = dump + tid * 48;
        for (int t = 0; t < 48; ++t) ins8(src[t], h);
#pragma unroll
        for (int q = 0; q < 8; ++q) topix[tid * 8 + q] = (int)(h[q] & 0x3FFu);
    }
    __syncthreads();

    // ---- exact fp32 rescore (bit-identical chain to R3..R16: single acc,
    // ascending k, score = fmaf(-2, acc, e2)) -> partition candidate lists
    float* base = out + OUT_QBASE;
    int* ibase = (int*)base;
    const int nit = nrows_blk >> 5;
    for (int it = 0; it < nit; ++it) {
        int rloc = it * 32 + (tid >> 3), cand = tid & 7;
        int el = topix[rloc * 8 + cand];
        int eg = eoff + el;
        const float* xp = xbase + (size_t)rloc * D;
        const float* ep = cb + (size_t)eg * D;
        float acc1 = 0.f;
#pragma unroll 4
        for (int qq = 0; qq < 64; ++qq) {
            float4 x = *(const float4*)(xp + qq * 4);
            float4 ee = *(const float4*)(ep + qq * 4);
            acc1 = fmaf(x.x, ee.x, acc1);
            acc1 = fmaf(x.y, ee.y, acc1);
            acc1 = fmaf(x.z, ee.z, acc1);
            acc1 = fmaf(x.w, ee.w, acc1);
        }
        float sc = fmaf(-2.f, acc1, e2full[eg]);
        if (is_class) {
            int p = blk - 512;
            base [C_SC + ((size_t)rloc * 8 + p) * 8 + cand] = sc;
            ibase[C_IX + ((size_t)rloc * 8 + p) * 8 + cand] = eg;
        } else {
            int rb = blk >> 3, pt = blk & 7;
            size_t gr = (size_t)rb * 256 + rloc;
            base [F_SC + (gr * 8 + pt) * 8 + cand] = sc;
            ibase[F_IX + (gr * 8 + pt) * 8 + cand] = eg;
        }
    }
#undef STAGE
}

// ---- final merge across the 8 partitions: exact top-3, indices + counts
// (separate kernel: must complete before vq_gather overwrites scratch)
__global__ __launch_bounds__(256)
void vq_fmerge(float* __restrict__ out, int* __restrict__ counts_f,
               int* __restrict__ counts_c)
{
    const int tid = threadIdx.x, blk = blockIdx.x;
    const float* base = out + OUT_QBASE;
    const int* ibase = (const int*)base;
    if (blk < 64) {
        size_t r = (size_t)blk * 256 + tid;   // feature row
        float fb[3] = {1e30f, 1e30f, 1e30f};
        int   fi[3] = {0x7FFFFFFF, 0x7FFFFFFF, 0x7FFFFFFF};
        for (int t = 0; t < 64; ++t)
            insert3(base[F_SC + r * 64 + t], ibase[F_IX + r * 64 + t], fb, fi);
#pragma unroll
        for (int s = 0; s < 3; ++s) {
            out[OUT_IDXBASE + (64 + r) * 3 + s] = (float)(fi[s] + NEC);
            atomicAdd(&counts_f[fi[s]], 1);
        }
    } else if (tid < 64) {
        size_t r = (size_t)tid;               // class row
        float fb[3] = {1e30f, 1e30f, 1e30f};
        int   fi[3] = {0x7FFFFFFF, 0x7FFFFFFF, 0x7FFFFFFF};
        for (int t = 0; t < 64; ++t)
            insert3(base[C_SC + r * 64 + t], ibase[C_IX + r * 64 + t], fb, fi);
#pragma unroll
        for (int s = 0; s < 3; ++s) {
            out[OUT_IDXBASE + r * 3 + s] = (float)fi[s];
            atomicAdd(&counts_c[fi[s]], 1);
        }
    }
}

// ---- gather emb[idx] -> quantized output + losses. One block per 64 rows
// (257 blocks; block 0 = class rows). Indices read back from OUT_IDXBASE.
__global__ __launch_bounds__(256)
void vq_gather(const float* __restrict__ features, const float* __restrict__ femb,
               const float* __restrict__ cemb, float* __restrict__ out,
               float* __restrict__ loss)
{
    __shared__ int sidx[192];
    __shared__ float red[256];
    const int tid = threadIdx.x, b = blockIdx.x;
    if (tid < 192) sidx[tid] = (int)out[OUT_IDXBASE + (size_t)b * 192 + tid];
    __syncthreads();
    const float* xb = features + (size_t)b * 64 * D;
    float lsum = 0.f;
    const int g = tid >> 4, l16 = tid & 15;
    for (int rs = g; rs < 192; rs += 16) {
        int rloc = rs / 3, slot = rs - rloc * 3;
        int idx = sidx[rs];
        const float* ep = (b == 0) ? cemb + (size_t)idx * D
                                   : femb + (size_t)(idx - NEC) * D;
        const float* xp = xb + (size_t)rloc * D;
        size_t ob = OUT_QBASE + (((size_t)b * 64 + rloc) * 3 + slot) * D;
#pragma unroll
        for (int qq = 0; qq < 4; ++qq) {
            int kk = (qq * 16 + l16) * 4;
            float4 e = *(const float4*)(ep + kk);
            float4 x = *(const float4*)(xp + kk);
            float dx = e.x - x.x, dy = e.y - x.y, dz = e.z - x.z, dw = e.w - x.w;
            lsum += dx * dx + dy * dy + dz * dz + dw * dw;
            // scalar stores: quantized region starts at out+1 (4B-aligned only)
            out[ob + kk + 0] = e.x; out[ob + kk + 1] = e.y;
            out[ob + kk + 2] = e.z; out[ob + kk + 3] = e.w;
        }
    }
    red[tid] = lsum;
    __syncthreads();
    for (int st = 128; st > 0; st >>= 1) {
        if (tid < st) red[tid] += red[tid + st];
        __syncthreads();
    }
    if (tid == 0) atomicAdd(b == 0 ? loss + 0 : loss + 1, red[0]);
}

// ---- scalar epilogue: perplexities + loss
__global__ __launch_bounds__(256)
void vq_finalize(float* __restrict__ out, const int* __restrict__ counts_f,
                 const int* __restrict__ counts_c, const float* __restrict__ loss)
{
    __shared__ double dred[256];
    const int tid = threadIdx.x;
    double acc = 0.0;
    for (int i = tid; i < NEF; i += 256) {
        double p = (double)counts_f[i] / 16384.0;
        acc += p * log(p + 1e-10);
    }
    dred[tid] = acc;
    __syncthreads();
    for (int st = 128; st > 0; st >>= 1) {
        if (tid < st) dred[tid] += dred[tid + st];
        __syncthreads();
    }
    double ent_f = -dred[0];
    __syncthreads();
    acc = 0.0;
    for (int i = tid; i < NEC; i += 256) {
        double p = (double)counts_c[i] / 64.0;
        acc += p * log(p + 1e-10);
    }
    dred[tid] = acc;
    __syncthreads();
    for (int st = 128; st > 0; st >>= 1) {
        if (tid < st) dred[tid] += dred[tid + st];
        __syncthreads();
    }
    double ent_c = -dred[0];
    if (tid == 0) {
        out[OUT_FPERP] = (float)exp(ent_f);
        out[OUT_CPERP] = (float)exp(ent_c);
        out[0] = 1.25f * (loss[0] / 49152.0f + loss[1] / 12582912.0f);
    }
}

extern "C" void kernel_launch(void* const* d_in, const int* in_sizes, int n_in,
                              void* d_out, int out_size, void* d_ws, size_t ws_size,
                              hipStream_t stream)
{
    const float* features = (const float*)d_in[0];  // [257*64, 256]
    const float* cemb     = (const float*)d_in[1];  // [1024, 256]
    const float* femb     = (const float*)d_in[2];  // [8192, 256]
    float* out = (float*)d_out;
    char*  ws  = (char*)d_ws;

    int*   counts_f = (int*)  (ws + WS_CNTF);
    int*   counts_c = (int*)  (ws + WS_CNTC);
    float* loss     = (float*)(ws + WS_LOSS);
    float* e2f      = (float*)(ws + WS_E2F);
    float* e2c      = (float*)(ws + WS_E2C);

    unsigned short* ebf_f = (unsigned short*)(out + OUT_QBASE + EBF_F);
    unsigned short* ebf_c = (unsigned short*)(out + OUT_QBASE + EBF_C);
    unsigned short* e2h_f = (unsigned short*)(out + OUT_QBASE + E2HF);
    unsigned short* e2h_c = (unsigned short*)(out + OUT_QBASE + E2HC);

    vq_prep<<<2304, 256, 0, stream>>>(femb, cemb, ebf_f, ebf_c, e2f, e2c,
                                      e2h_f, e2h_c, counts_f, counts_c, loss);
    vq_coarse<<<520, 256, 0, stream>>>(features, ebf_f, ebf_c, femb, cemb,
                                       e2f, e2c, e2h_f, e2h_c, out);
    vq_fmerge<<<65, 256, 0, stream>>>(out, counts_f, counts_c);
    vq_gather<<<257, 256, 0, stream>>>(features, femb, cemb, out, loss);
    vq_finalize<<<1, 256, 0, stream>>>(out, counts_f, counts_c, loss);
}

// Round 14
// 268.894 us; speedup vs baseline: 1.1824x; 1.1824x over previous
//
#include <hip/hip_runtime.h>
#include <math.h>

// Problem dims
#define D 256
#define NEF 8192        // feature codebook
#define NEC 1024        // class codebook

// Output layout (flat float32): loss | quantized[257*64*3*256] | f_perp | c_perp | idx[257*64*3]
#define OUT_QBASE   1
#define OUT_FPERP   12632065
#define OUT_CPERP   12632066
#define OUT_IDXBASE 12632067

// Scratch inside the quantized output region (rewritten by vq_gather later;
// fmerge completes before gather launches -> no overlap race). Float offsets.
// R18: 6 uneven feature partitions (43/43/43/43/42/42 chunks) x 8 cands.
#define F_SC  0           // feature rescored scores [16384 row][6 part][8]
#define F_IX  786432      // feature candidate codebook idx (int view)
#define C_SC  1572864     // class rescored scores [64 row][4 part][8]
#define C_IX  1574912
#define E2HF  1576963     // u16 biased e2, feature (4096 float slots; byte%16==0)
#define E2HC  1581059     // u16 biased e2, class (512 float slots; byte%16==0)
#define EBF_F 1581575     // bf16 feature codebook, row-major (byte addr %16==0)
#define EBF_C 2630151     // bf16 class codebook (ends 2761223 << OUT_FPERP)

// Workspace layout (bytes)
#define WS_CNTF  0        // 8192 int
#define WS_CNTC  32768    // 1024 int
#define WS_LOSS  36864    // float[2]: loss_c, loss_f
#define WS_E2F   49152    // 8192 float
#define WS_E2C   81920    // 1024 float

typedef short bf8 __attribute__((ext_vector_type(8)));     // 8 bf16 (4 VGPRs)
typedef float f32x4 __attribute__((ext_vector_type(4)));   // MFMA C/D frag

// float -> bf16 bits, round-to-nearest-even (coarse pass only)
__device__ __forceinline__ unsigned f2bf(float f) {
    union { float f; unsigned u; } v; v.f = f;
    return (v.u + 0x7FFFu + ((v.u >> 16) & 1u)) >> 16;
}

// async global(16B/lane) -> LDS (linear, wave-uniform base + lane*16)
__device__ __forceinline__ void gload_lds16(const void* g, void* l) {
    __builtin_amdgcn_global_load_lds(
        (const __attribute__((address_space(1))) void*)g,
        (__attribute__((address_space(3))) void*)l, 16, 0, 0);
}

// single-instruction u32 median-of-3 (gfx9+ V_MED3_U32)
#define MED3U(d, a, b_, c_) \
    asm("v_med3_u32 %0, %1, %2, %3" : "=v"(d) : "v"(a), "v"(b_), "v"(c_))

// Lexicographic (score, idx) insert — EXACT-path only (fmerge). Matches
// jax.lax.top_k stable tie-breaking.
__device__ __forceinline__ void insert3(float s, int idx, float* bs, int* bi) {
    bool lt2 = (s < bs[2]) || (s == bs[2] && idx < bi[2]);
    if (lt2) {
        bool lt1 = (s < bs[1]) || (s == bs[1] && idx < bi[1]);
        if (lt1) {
            bs[2] = bs[1]; bi[2] = bi[1];
            bool lt0 = (s < bs[0]) || (s == bs[0] && idx < bi[0]);
            if (lt0) { bs[1] = bs[0]; bi[1] = bi[0]; bs[0] = s; bi[0] = idx; }
            else     { bs[1] = s;     bi[1] = idx; }
        } else       { bs[2] = s;     bi[2] = idx; }
    }
}

// Coarse packed-u32 top-8 insert (merge phase)
__device__ __forceinline__ void ins8(unsigned p, unsigned* h) {
    if (p < h[7]) {
        h[7] = p;
#pragma unroll
        for (int q = 7; q > 0; --q)
            if (h[q] < h[q - 1]) { unsigned t = h[q]; h[q] = h[q - 1]; h[q - 1] = t; }
    }
}

// ---- fused: codebook norms + fp32->bf16 convert + workspace zeroing.
// Also emits u16 fixed-point biased norms (e2+1024)*32 for the coarse pass
// (error <= 0.016, 8x finer than the 0.125 coarse pack truncation).
__global__ __launch_bounds__(256)
void vq_prep(const float* __restrict__ femb, const float* __restrict__ cemb,
             unsigned short* __restrict__ ebf_f, unsigned short* __restrict__ ebf_c,
             float* __restrict__ e2f, float* __restrict__ e2c,
             unsigned short* __restrict__ e2h_f, unsigned short* __restrict__ e2h_c,
             int* __restrict__ counts_f, int* __restrict__ counts_c,
             float* __restrict__ loss)
{
    int zid = blockIdx.x * 256 + threadIdx.x;
    if (zid < 8192)      counts_f[zid] = 0;
    else if (zid < 9216) counts_c[zid - 8192] = 0;
    else if (zid < 9218) loss[zid - 9216] = 0.f;

    int wave = blockIdx.x * 4 + (threadIdx.x >> 6);
    int lane = threadIdx.x & 63;
    const float* src; unsigned short* dst; float* ndst; unsigned short* nh;
    if (wave < NEF) { src = femb + (size_t)wave * D; dst = ebf_f + (size_t)wave * D; ndst = e2f + wave; nh = e2h_f + wave; }
    else { int w2 = wave - NEF; src = cemb + (size_t)w2 * D; dst = ebf_c + (size_t)w2 * D; ndst = e2c + w2; nh = e2h_c + w2; }
    float4 v = *(const float4*)(src + lane * 4);
    uint2 o;
    o.x = f2bf(v.x) | (f2bf(v.y) << 16);
    o.y = f2bf(v.z) | (f2bf(v.w) << 16);
    *(uint2*)(dst + lane * 4) = o;
    float s = v.x * v.x + v.y * v.y + v.z * v.z + v.w * v.w;
#pragma unroll
    for (int off = 32; off > 0; off >>= 1) s += __shfl_down(s, off);
    if (lane == 0) {
        *ndst = s;
        *nh = (unsigned short)__float2int_rn((s + 1024.f) * 32.f);
    }
}

// ---- coarse pass, R18 structure: exact R16 per-block machinery, regridded
// for 3 INDEPENDENT blocks/CU. 6 uneven emb-partitions (43/43/43/43/42/42
// chunks of 32) x 128 row-blocks -> grid 768 feature = EXACTLY 3 blocks/CU,
// single round, no tail (+4 class). Block = 128 rows x partition, 4 waves
// x 32 rows, A in regs (76 VGPR — fits 12 waves/CU). B per 32-emb chunk
// (16KB) via global_load_lds w16, ring-3 (48KB), depth-2 prefetch, RAW
// s_barrier + counted vmcnt(4). e2 u16 biased in LDS (2816B). LDS 50.75KB
// -> 3 blocks/CU = 12 waves = 3/SIMD of independent blocks: one block's
// barrier stall hides under another's compute (the lever R14's single
// lockstep block couldn't provide).
__global__ __launch_bounds__(256, 2)
void vq_coarse(const float* __restrict__ features,
               const unsigned short* __restrict__ ebf_f,
               const unsigned short* __restrict__ ebf_c,
               const float* __restrict__ femb, const float* __restrict__ cemb,
               const float* __restrict__ e2f, const float* __restrict__ e2c,
               const unsigned short* __restrict__ e2h_f,
               const unsigned short* __restrict__ e2h_c,
               float* __restrict__ out)
{
    __shared__ uint4 sm[3248];   // 51968B: B ring buf0..2 [0,48KB), e2u16 [48KB,+2816)
                                 // post-loop overlay in bufs: dump[128][49] + topix[128][8]
    const int tid = threadIdx.x, lane = tid & 63, w = tid >> 6;
    const int l15 = lane & 15, q4 = lane >> 4;
    const int blk = blockIdx.x;
    const bool is_class = blk >= 768;

    const float* xbase;            // block's first row (fp32 features)
    const char* ebase8;            // partition base in bf16 codebook (bytes)
    const unsigned short* e2hp;    // partition u16 biased norms
    const float* cb; const float* e2full;
    int nch, eoff, nrows_blk, npart, pt, rb;
    if (is_class) {
        pt = blk - 768; rb = 0;
        xbase = features;                      // class rows 0..63
        eoff = pt * 256; nch = 8; nrows_blk = 64; npart = 256;
        ebase8 = (const char*)(ebf_c + (size_t)eoff * D);
        e2hp = e2h_c + eoff; cb = cemb; e2full = e2c;
    } else {
        rb = blk / 6; pt = blk - rb * 6;
        xbase = features + (size_t)(64 + rb * 128) * D;
        int cs = pt * 42 + (pt < 4 ? pt : 4);  // chunk start (uneven split)
        nch = (pt < 4) ? 43 : 42;
        eoff = cs * 32; nrows_blk = 128; npart = nch * 32;
        ebase8 = (const char*)(ebf_f + (size_t)eoff * D);
        e2hp = e2h_f + eoff; cb = femb; e2full = e2f;
    }

    // class blocks: only waves 0,1 carry rows (64 rows); 2,3 stage+barrier only
    const bool active = !is_class || (w < 2);

    // ---- staging constants (R7/R16-verified swizzle, 16KB chunk = 4 loads/thr).
    // LDS linear byte L = ring + tid*16 + p*4096 holds chunk byte (L ^ xv),
    // xv = ((L>>9)&7)<<4 = ((tid>>5)&7)<<4 (p*4096, ring*16384 are 0 mod 8
    // in L>>9). Reader applies the same XOR.
    const unsigned xv = ((unsigned)(tid >> 5) & 7u) << 4;
    unsigned soff[4];
#pragma unroll
    for (int p = 0; p < 4; ++p)
        soff[p] = ((unsigned)(tid * 16 + p * 4096)) ^ xv;
    char* const lwb = (char*)sm + (size_t)w * 1024;   // wave's linear LDS base

#define STAGE(C, B_) {                                                          \
    const char* cb8_ = ebase8 + (size_t)(C) * 16384;                            \
    char* lb_ = lwb + (B_) * 16384;                                             \
    _Pragma("unroll")                                                           \
    for (int p = 0; p < 4; ++p)                                                 \
        gload_lds16(cb8_ + soff[p], lb_ + p * 4096);                            \
}

    // per-lane swizzled B-frag read offset pieces: logical
    // P = (j*16+l15)*512 + s*64 + q4*16, read addr = P ^ ((l15&7)<<4)
    const unsigned rq = ((unsigned)(q4 * 16)) ^ (((unsigned)(l15 & 7)) << 4);
    const unsigned lrow = (unsigned)l15 * 512;

    unsigned short* const e2s16 = (unsigned short*)((char*)sm + 49152);  // u16 biased

    unsigned t3[2][4][3];
#pragma unroll
    for (int i = 0; i < 2; ++i)
#pragma unroll
        for (int r = 0; r < 4; ++r)
#pragma unroll
            for (int s3 = 0; s3 < 3; ++s3) t3[i][r][s3] = 0xFFFFFFFFu;

    // ---- prologue: u16 e2 partition -> LDS; A frags -> regs (verified
    // pattern: lane holds X[row = w*32 + i*16 + l15][k = s*32 + q4*8 .. +8]).
    // The one-time __syncthreads drains these loads so the main loop's vmcnt
    // queue contains ONLY stage loads (counted waits stay exact).
    for (int i4 = tid; i4 < ((npart + 7) >> 3); i4 += 256)
        ((uint4*)e2s16)[i4] = ((const uint4*)e2hp)[i4];
    bf8 A[2][8];
    if (active) {
        const float* xw = xbase + (size_t)(w * 32 + l15) * D + q4 * 8;
#pragma unroll
        for (int i = 0; i < 2; ++i)
#pragma unroll
            for (int s = 0; s < 8; ++s) {
                const float* p = xw + i * 16 * D + s * 32;
                float4 a = *(const float4*)p;
                float4 b = *(const float4*)(p + 4);
                uint4 o;
                o.x = f2bf(a.x) | (f2bf(a.y) << 16);
                o.y = f2bf(a.z) | (f2bf(a.w) << 16);
                o.z = f2bf(b.x) | (f2bf(b.y) << 16);
                o.w = f2bf(b.z) | (f2bf(b.w) << 16);
                A[i][s] = *(bf8*)&o;
            }
    }
    __syncthreads();   // e2 visible; A/e2 loads drained

    // e2 rotation regs for chunk 0 (LDS u16 -> biased float)
    float e2c0 = (float)e2s16[l15] * 0.03125f;
    float e2c1 = (float)e2s16[16 + l15] * 0.03125f;

    // depth-2 prefetch: chunks 0,1 into ring 0,1
    STAGE(0, 0)
    STAGE(1, 1)

    // ---- main loop: one RAW barrier per 32-emb chunk, counted vmcnt.
    // At iter c the queue holds (oldest-first) chunks c, c+1 (4 loads each);
    // vmcnt(4) retires exactly chunk c. STAGE(c+2) reuses the ring slot last
    // read at iter c-1 — all waves passed that compute before this barrier.
#pragma unroll 1
    for (int c = 0; c < nch; ++c) {
        const int rem = nch - 1 - c;
        if (rem >= 1) asm volatile("s_waitcnt vmcnt(4)" ::: "memory");
        else          asm volatile("s_waitcnt vmcnt(0)" ::: "memory");
        __builtin_amdgcn_s_barrier();
        asm volatile("" ::: "memory");
        if (c + 2 < nch) STAGE(c + 2, (c + 2) % 3)
        if (active) {
            // prefetch next chunk's e2 pair (consumed next iteration; the
            // ds_read latency hides under this chunk's MFMAs)
            float e2n0 = 0.f, e2n1 = 0.f;
            if (c + 1 < nch) {
                e2n0 = (float)e2s16[(c + 1) * 32 + l15] * 0.03125f;
                e2n1 = (float)e2s16[(c + 1) * 32 + 16 + l15] * 0.03125f;
            }
            const char* bb = (const char*)sm + (c % 3) * 16384;
            f32x4 acc[2][2];
#pragma unroll
            for (int i = 0; i < 2; ++i)
#pragma unroll
                for (int j = 0; j < 2; ++j) acc[i][j] = (f32x4){0.f, 0.f, 0.f, 0.f};
            __builtin_amdgcn_s_setprio(1);
#pragma unroll
            for (int s = 0; s < 8; ++s) {
                const char* ba = bb + lrow + (rq ^ (unsigned)(s << 6));
                bf8 bv0 = *(const bf8*)(ba);
                bf8 bv1 = *(const bf8*)(ba + 8192);
                acc[0][0] = __builtin_amdgcn_mfma_f32_16x16x32_bf16(A[0][s], bv0, acc[0][0], 0, 0, 0);
                acc[1][0] = __builtin_amdgcn_mfma_f32_16x16x32_bf16(A[1][s], bv0, acc[1][0], 0, 0, 0);
                acc[0][1] = __builtin_amdgcn_mfma_f32_16x16x32_bf16(A[0][s], bv1, acc[0][1], 0, 0, 0);
                acc[1][1] = __builtin_amdgcn_mfma_f32_16x16x32_bf16(A[1][s], bv1, acc[1][1], 0, 0, 0);
            }
            __builtin_amdgcn_s_setprio(0);
            // fold chunk scores into per-lane packed top-3.
            // 6 ops/score: fmaf, and_or pack (positive-monotone bits, bias
            // guarantees sc>0), min/med3/max/min. 11-bit idx, 21-bit score.
#pragma unroll
            for (int j = 0; j < 2; ++j) {
                const float e2v = j ? e2c1 : e2c0;
                const unsigned elb = (unsigned)(c * 32 + j * 16 + l15);
#pragma unroll
                for (int i = 0; i < 2; ++i)
#pragma unroll
                    for (int r = 0; r < 4; ++r) {
                        float sc = fmaf(-2.f, acc[i][j][r], e2v);
                        unsigned u = __float_as_uint(sc);
                        unsigned p = (u & 0xFFFFF800u) | elb;
                        unsigned* b = t3[i][r];
                        unsigned n0 = p < b[0] ? p : b[0];
                        unsigned n1; MED3U(n1, p, b[0], b[1]);
                        unsigned x1 = p > b[1] ? p : b[1];
                        unsigned n2 = x1 < b[2] ? x1 : b[2];
                        b[0] = n0; b[1] = n1; b[2] = n2;
                    }
            }
            e2c0 = e2n0; e2c1 = e2n1;
        }
    }
    __syncthreads();   // all reads done; vmcnt already 0 — safe to overlay

    // ---- dump per-lane packed top-3 -> LDS overlay (stride 49 u32)
    unsigned* dump = (unsigned*)sm;            // [128][49]
    int* topix = (int*)sm + 128 * 49;          // [128][8]
    if (active) {
#pragma unroll
        for (int i = 0; i < 2; ++i)
#pragma unroll
            for (int r = 0; r < 4; ++r) {
                int row = w * 32 + i * 16 + q4 * 4 + r;  // C layout: row=q4*4+reg
#pragma unroll
                for (int s3 = 0; s3 < 3; ++s3)
                    dump[row * 49 + l15 * 3 + s3] = t3[i][r][s3];
            }
    }
    __syncthreads();

    // ---- per-row merge: 16 lanes x top-3 (48 cands) -> coarse top-8
    if (tid < nrows_blk) {
        unsigned h[8];
#pragma unroll
        for (int q = 0; q < 8; ++q) h[q] = 0xFFFFFFFFu;
        const unsigned* src = dump + tid * 49;
        for (int t = 0; t < 48; ++t) ins8(src[t], h);
#pragma unroll
        for (int q = 0; q < 8; ++q) topix[tid * 8 + q] = (int)(h[q] & 0x7FFu);
    }
    __syncthreads();

    // ---- exact fp32 rescore (bit-identical chain to R3..R17: single acc,
    // ascending k, score = fmaf(-2, acc, e2)) -> partition candidate lists
    float* base = out + OUT_QBASE;
    int* ibase = (int*)base;
    const int nit = nrows_blk >> 5;
    for (int it = 0; it < nit; ++it) {
        int rloc = it * 32 + (tid >> 3), cand = tid & 7;
        int el = topix[rloc * 8 + cand];
        int eg = eoff + el;
        const float* xp = xbase + (size_t)rloc * D;
        const float* ep = cb + (size_t)eg * D;
        float acc1 = 0.f;
#pragma unroll 4
        for (int qq = 0; qq < 64; ++qq) {
            float4 x = *(const float4*)(xp + qq * 4);
            float4 ee = *(const float4*)(ep + qq * 4);
            acc1 = fmaf(x.x, ee.x, acc1);
            acc1 = fmaf(x.y, ee.y, acc1);
            acc1 = fmaf(x.z, ee.z, acc1);
            acc1 = fmaf(x.w, ee.w, acc1);
        }
        float sc = fmaf(-2.f, acc1, e2full[eg]);
        if (is_class) {
            base [C_SC + ((size_t)rloc * 4 + pt) * 8 + cand] = sc;
            ibase[C_IX + ((size_t)rloc * 4 + pt) * 8 + cand] = eg;
        } else {
            size_t gr = (size_t)rb * 128 + rloc;
            base [F_SC + (gr * 6 + pt) * 8 + cand] = sc;
            ibase[F_IX + (gr * 6 + pt) * 8 + cand] = eg;
        }
    }
#undef STAGE
}

// ---- final merge across the partitions: exact top-3, indices + counts
// (separate kernel: must complete before vq_gather overwrites scratch)
__global__ __launch_bounds__(256)
void vq_fmerge(float* __restrict__ out, int* __restrict__ counts_f,
               int* __restrict__ counts_c)
{
    const int tid = threadIdx.x, blk = blockIdx.x;
    const float* base = out + OUT_QBASE;
    const int* ibase = (const int*)base;
    if (blk < 64) {
        size_t r = (size_t)blk * 256 + tid;   // feature row: 6 parts x 8 = 48
        float fb[3] = {1e30f, 1e30f, 1e30f};
        int   fi[3] = {0x7FFFFFFF, 0x7FFFFFFF, 0x7FFFFFFF};
        for (int t = 0; t < 48; ++t)
            insert3(base[F_SC + r * 48 + t], ibase[F_IX + r * 48 + t], fb, fi);
#pragma unroll
        for (int s = 0; s < 3; ++s) {
            out[OUT_IDXBASE + (64 + r) * 3 + s] = (float)(fi[s] + NEC);
            atomicAdd(&counts_f[fi[s]], 1);
        }
    } else if (tid < 64) {
        size_t r = (size_t)tid;               // class row: 4 parts x 8 = 32
        float fb[3] = {1e30f, 1e30f, 1e30f};
        int   fi[3] = {0x7FFFFFFF, 0x7FFFFFFF, 0x7FFFFFFF};
        for (int t = 0; t < 32; ++t)
            insert3(base[C_SC + r * 32 + t], ibase[C_IX + r * 32 + t], fb, fi);
#pragma unroll
        for (int s = 0; s < 3; ++s) {
            out[OUT_IDXBASE + r * 3 + s] = (float)fi[s];
            atomicAdd(&counts_c[fi[s]], 1);
        }
    }
}

// ---- gather emb[idx] -> quantized output + losses. One block per 64 rows
// (257 blocks; block 0 = class rows). Indices read back from OUT_IDXBASE.
__global__ __launch_bounds__(256)
void vq_gather(const float* __restrict__ features, const float* __restrict__ femb,
               const float* __restrict__ cemb, float* __restrict__ out,
               float* __restrict__ loss)
{
    __shared__ int sidx[192];
    __shared__ float red[256];
    const int tid = threadIdx.x, b = blockIdx.x;
    if (tid < 192) sidx[tid] = (int)out[OUT_IDXBASE + (size_t)b * 192 + tid];
    __syncthreads();
    const float* xb = features + (size_t)b * 64 * D;
    float lsum = 0.f;
    const int g = tid >> 4, l16 = tid & 15;
    for (int rs = g; rs < 192; rs += 16) {
        int rloc = rs / 3, slot = rs - rloc * 3;
        int idx = sidx[rs];
        const float* ep = (b == 0) ? cemb + (size_t)idx * D
                                   : femb + (size_t)(idx - NEC) * D;
        const float* xp = xb + (size_t)rloc * D;
        size_t ob = OUT_QBASE + (((size_t)b * 64 + rloc) * 3 + slot) * D;
#pragma unroll
        for (int qq = 0; qq < 4; ++qq) {
            int kk = (qq * 16 + l16) * 4;
            float4 e = *(const float4*)(ep + kk);
            float4 x = *(const float4*)(xp + kk);
            float dx = e.x - x.x, dy = e.y - x.y, dz = e.z - x.z, dw = e.w - x.w;
            lsum += dx * dx + dy * dy + dz * dz + dw * dw;
            // scalar stores: quantized region starts at out+1 (4B-aligned only)
            out[ob + kk + 0] = e.x; out[ob + kk + 1] = e.y;
            out[ob + kk + 2] = e.z; out[ob + kk + 3] = e.w;
        }
    }
    red[tid] = lsum;
    __syncthreads();
    for (int st = 128; st > 0; st >>= 1) {
        if (tid < st) red[tid] += red[tid + st];
        __syncthreads();
    }
    if (tid == 0) atomicAdd(b == 0 ? loss + 0 : loss + 1, red[0]);
}

// ---- scalar epilogue: perplexities + loss
__global__ __launch_bounds__(256)
void vq_finalize(float* __restrict__ out, const int* __restrict__ counts_f,
                 const int* __restrict__ counts_c, const float* __restrict__ loss)
{
    __shared__ double dred[256];
    const int tid = threadIdx.x;
    double acc = 0.0;
    for (int i = tid; i < NEF; i += 256) {
        double p = (double)counts_f[i] / 16384.0;
        acc += p * log(p + 1e-10);
    }
    dred[tid] = acc;
    __syncthreads();
    for (int st = 128; st > 0; st >>= 1) {
        if (tid < st) dred[tid] += dred[tid + st];
        __syncthreads();
    }
    double ent_f = -dred[0];
    __syncthreads();
    acc = 0.0;
    for (int i = tid; i < NEC; i += 256) {
        double p = (double)counts_c[i] / 64.0;
        acc += p * log(p + 1e-10);
    }
    dred[tid] = acc;
    __syncthreads();
    for (int st = 128; st > 0; st >>= 1) {
        if (tid < st) dred[tid] += dred[tid + st];
        __syncthreads();
    }
    double ent_c = -dred[0];
    if (tid == 0) {
        out[OUT_FPERP] = (float)exp(ent_f);
        out[OUT_CPERP] = (float)exp(ent_c);
        out[0] = 1.25f * (loss[0] / 49152.0f + loss[1] / 12582912.0f);
    }
}

extern "C" void kernel_launch(void* const* d_in, const int* in_sizes, int n_in,
                              void* d_out, int out_size, void* d_ws, size_t ws_size,
                              hipStream_t stream)
{
    const float* features = (const float*)d_in[0];  // [257*64, 256]
    const float* cemb     = (const float*)d_in[1];  // [1024, 256]
    const float* femb     = (const float*)d_in[2];  // [8192, 256]
    float* out = (float*)d_out;
    char*  ws  = (char*)d_ws;

    int*   counts_f = (int*)  (ws + WS_CNTF);
    int*   counts_c = (int*)  (ws + WS_CNTC);
    float* loss     = (float*)(ws + WS_LOSS);
    float* e2f      = (float*)(ws + WS_E2F);
    float* e2c      = (float*)(ws + WS_E2C);

    unsigned short* ebf_f = (unsigned short*)(out + OUT_QBASE + EBF_F);
    unsigned short* ebf_c = (unsigned short*)(out + OUT_QBASE + EBF_C);
    unsigned short* e2h_f = (unsigned short*)(out + OUT_QBASE + E2HF);
    unsigned short* e2h_c = (unsigned short*)(out + OUT_QBASE + E2HC);

    vq_prep<<<2304, 256, 0, stream>>>(femb, cemb, ebf_f, ebf_c, e2f, e2c,
                                      e2h_f, e2h_c, counts_f, counts_c, loss);
    vq_coarse<<<772, 256, 0, stream>>>(features, ebf_f, ebf_c, femb, cemb,
                                       e2f, e2c, e2h_f, e2h_c, out);
    vq_fmerge<<<65, 256, 0, stream>>>(out, counts_f, counts_c);
    vq_gather<<<257, 256, 0, stream>>>(features, femb, cemb, out, loss);
    vq_finalize<<<1, 256, 0, stream>>>(out, counts_f, counts_c, loss);
}

// Round 16
// 222.655 us; speedup vs baseline: 1.4280x; 1.2077x over previous
//
#include <hip/hip_runtime.h>
#include <math.h>

// Problem dims
#define D 256
#define NEF 8192        // feature codebook
#define NEC 1024        // class codebook

// Output layout (flat float32): loss | quantized[257*64*3*256] | f_perp | c_perp | idx[257*64*3]
#define OUT_QBASE   1
#define OUT_FPERP   12632065
#define OUT_CPERP   12632066
#define OUT_IDXBASE 12632067

// Scratch inside the quantized output region (rewritten by vq_gather later;
// fmerge completes before gather launches -> no overlap race). Float offsets
// (R9/R12-verified 4-partition layout):
#define F_SC  0           // feature rescored scores [16384 row][4 part][8]
#define F_IX  524288      // feature candidate codebook idx (int view)
#define C_SC  1048576     // class   rescored scores [64 row][4 part][8]
#define C_IX  1050624
#define E2HF  1052679     // u16 biased e2 of feature codebook, 4096 float slots
#define E2HC  1056775     // u16 biased e2 of class codebook (E2HF + 4096)
#define EBF_F 1064963     // bf16 feature codebook, row-major (byte addr %16==0)
#define EBF_C 2113539     // bf16 class codebook

// Workspace layout (bytes)
#define WS_CNTF  0        // 8192 int
#define WS_CNTC  32768    // 1024 int
#define WS_LOSS  36864    // float[2]: loss_c, loss_f
#define WS_E2F   49152    // 8192 float
#define WS_E2C   81920    // 1024 float

typedef short bf8 __attribute__((ext_vector_type(8)));     // 8 bf16 (4 VGPRs)
typedef float f32x4 __attribute__((ext_vector_type(4)));   // MFMA C/D frag

// float -> bf16 bits, round-to-nearest-even (coarse pass only)
__device__ __forceinline__ unsigned f2bf(float f) {
    union { float f; unsigned u; } v; v.f = f;
    return (v.u + 0x7FFFu + ((v.u >> 16) & 1u)) >> 16;
}

// async global(16B/lane) -> LDS (linear, wave-uniform base + lane*16)
__device__ __forceinline__ void gload_lds16(const void* g, void* l) {
    __builtin_amdgcn_global_load_lds(
        (const __attribute__((address_space(1))) void*)g,
        (__attribute__((address_space(3))) void*)l, 16, 0, 0);
}

// single-instruction u32 median-of-3 (gfx9+ V_MED3_U32)
#define MED3U(d, a, b_, c_) \
    asm("v_med3_u32 %0, %1, %2, %3" : "=v"(d) : "v"(a), "v"(b_), "v"(c_))

// Lexicographic (score, idx) insert — EXACT-path only (fmerge). Matches
// jax.lax.top_k stable tie-breaking.
__device__ __forceinline__ void insert3(float s, int idx, float* bs, int* bi) {
    bool lt2 = (s < bs[2]) || (s == bs[2] && idx < bi[2]);
    if (lt2) {
        bool lt1 = (s < bs[1]) || (s == bs[1] && idx < bi[1]);
        if (lt1) {
            bs[2] = bs[1]; bi[2] = bi[1];
            bool lt0 = (s < bs[0]) || (s == bs[0] && idx < bi[0]);
            if (lt0) { bs[1] = bs[0]; bi[1] = bi[0]; bs[0] = s; bi[0] = idx; }
            else     { bs[1] = s;     bi[1] = idx; }
        } else       { bs[2] = s;     bi[2] = idx; }
    }
}

// Coarse packed-u32 top-8 insert (merge phase)
__device__ __forceinline__ void ins8(unsigned p, unsigned* h) {
    if (p < h[7]) {
        h[7] = p;
#pragma unroll
        for (int q = 7; q > 0; --q)
            if (h[q] < h[q - 1]) { unsigned t = h[q]; h[q] = h[q - 1]; h[q - 1] = t; }
    }
}

// ---- fused: codebook norms + fp32->bf16 convert + workspace zeroing.
// Also emits u16 fixed-point biased norms (e2+1024)*32 for the coarse pass
// (error <= 0.016, 8x finer than the 0.125 coarse pack truncation).
__global__ __launch_bounds__(256)
void vq_prep(const float* __restrict__ femb, const float* __restrict__ cemb,
             unsigned short* __restrict__ ebf_f, unsigned short* __restrict__ ebf_c,
             float* __restrict__ e2f, float* __restrict__ e2c,
             unsigned short* __restrict__ e2h_f, unsigned short* __restrict__ e2h_c,
             int* __restrict__ counts_f, int* __restrict__ counts_c,
             float* __restrict__ loss)
{
    int zid = blockIdx.x * 256 + threadIdx.x;
    if (zid < 8192)      counts_f[zid] = 0;
    else if (zid < 9216) counts_c[zid - 8192] = 0;
    else if (zid < 9218) loss[zid - 9216] = 0.f;

    int wave = blockIdx.x * 4 + (threadIdx.x >> 6);
    int lane = threadIdx.x & 63;
    const float* src; unsigned short* dst; float* ndst; unsigned short* nh;
    if (wave < NEF) { src = femb + (size_t)wave * D; dst = ebf_f + (size_t)wave * D; ndst = e2f + wave; nh = e2h_f + wave; }
    else { int w2 = wave - NEF; src = cemb + (size_t)w2 * D; dst = ebf_c + (size_t)w2 * D; ndst = e2c + w2; nh = e2h_c + w2; }
    float4 v = *(const float4*)(src + lane * 4);
    uint2 o;
    o.x = f2bf(v.x) | (f2bf(v.y) << 16);
    o.y = f2bf(v.z) | (f2bf(v.w) << 16);
    *(uint2*)(dst + lane * 4) = o;
    float s = v.x * v.x + v.y * v.y + v.z * v.z + v.w * v.w;
#pragma unroll
    for (int off = 32; off > 0; off >>= 1) s += __shfl_down(s, off);
    if (lane == 0) {
        *ndst = s;
        *nh = (unsigned short)__float2int_rn((s + 1024.f) * 32.f);
    }
}

// ---- coarse pass = exact R16 (best measured: 174.8us coarse / 223us
// total). Block = 128 rows x 2048-emb partition (4 partitions, pt=blk&3 —
// XCD-aligned, the locality sweet spot per R18's L2-thrash failure), 4
// waves x 32 rows. A (32x256 bf16) in regs. B streamed per 32-emb chunk
// (16KB) via global_load_lds w16 into a 3-deep ring (48KB), depth-2
// prefetch, RAW s_barrier + counted s_waitcnt vmcnt(4). e2 in LDS as u16
// fixed-point biased (+1024)*32 (4KB) -> all coarse scores positive ->
// pack = single and_or; insert = min/med3/max/min; e2 pair for chunk c+1
// rotates through regs. Grid 516 = 512 feature (single round) + 4 class.
__global__ __launch_bounds__(256, 2)
void vq_coarse(const float* __restrict__ features,
               const unsigned short* __restrict__ ebf_f,
               const unsigned short* __restrict__ ebf_c,
               const float* __restrict__ femb, const float* __restrict__ cemb,
               const float* __restrict__ e2f, const float* __restrict__ e2c,
               const unsigned short* __restrict__ e2h_f,
               const unsigned short* __restrict__ e2h_c,
               float* __restrict__ out)
{
    __shared__ uint4 sm[3328];   // 52KB: B ring buf0..2 [0,48KB), e2u16 [48KB,52KB)
                                 // post-loop overlay in bufs: dump[128][49] + topix[128][8]
    const int tid = threadIdx.x, lane = tid & 63, w = tid >> 6;
    const int l15 = lane & 15, q4 = lane >> 4;
    const int blk = blockIdx.x;
    const bool is_class = blk >= 512;

    const float* xbase;            // block's first row (fp32 features)
    const char* ebase8;            // partition base in bf16 codebook (bytes)
    const unsigned short* e2hp;    // partition u16 biased norms
    const float* cb; const float* e2full;
    int nch, eoff, nrows_blk, npart;
    if (is_class) {
        int p = blk - 512;
        xbase = features;                      // class rows 0..63
        eoff = p * 256; nch = 8; nrows_blk = 64; npart = 256;
        ebase8 = (const char*)(ebf_c + (size_t)eoff * D);
        e2hp = e2h_c + eoff; cb = cemb; e2full = e2c;
    } else {
        int rb = blk >> 2, pt = blk & 3;
        xbase = features + (size_t)(64 + rb * 128) * D;
        eoff = pt * 2048; nch = 64; nrows_blk = 128; npart = 2048;
        ebase8 = (const char*)(ebf_f + (size_t)eoff * D);
        e2hp = e2h_f + eoff; cb = femb; e2full = e2f;
    }

    // class blocks: only waves 0,1 carry rows (64 rows); 2,3 stage+barrier only
    const bool active = !is_class || (w < 2);

    // ---- staging constants (R7/R9-verified swizzle, 16KB chunk = 4 loads/thr).
    // LDS linear byte L = ring + tid*16 + p*4096 holds chunk byte (L ^ xv),
    // xv = ((L>>9)&7)<<4 = ((tid>>5)&7)<<4 (p*4096, ring*16384 are 0 mod 8
    // in L>>9). Reader applies the same XOR.
    const unsigned xv = ((unsigned)(tid >> 5) & 7u) << 4;
    unsigned soff[4];
#pragma unroll
    for (int p = 0; p < 4; ++p)
        soff[p] = ((unsigned)(tid * 16 + p * 4096)) ^ xv;
    char* const lwb = (char*)sm + (size_t)w * 1024;   // wave's linear LDS base

#define STAGE(C, B_) {                                                          \
    const char* cb8_ = ebase8 + (size_t)(C) * 16384;                            \
    char* lb_ = lwb + (B_) * 16384;                                             \
    _Pragma("unroll")                                                           \
    for (int p = 0; p < 4; ++p)                                                 \
        gload_lds16(cb8_ + soff[p], lb_ + p * 4096);                            \
}

    // per-lane swizzled B-frag read offset pieces: logical
    // P = (j*16+l15)*512 + s*64 + q4*16, read addr = P ^ ((l15&7)<<4)
    const unsigned rq = ((unsigned)(q4 * 16)) ^ (((unsigned)(l15 & 7)) << 4);
    const unsigned lrow = (unsigned)l15 * 512;

    unsigned short* const e2s16 = (unsigned short*)((char*)sm + 49152);  // u16 biased

    unsigned t3[2][4][3];
#pragma unroll
    for (int i = 0; i < 2; ++i)
#pragma unroll
        for (int r = 0; r < 4; ++r)
#pragma unroll
            for (int s3 = 0; s3 < 3; ++s3) t3[i][r][s3] = 0xFFFFFFFFu;

    // ---- prologue: u16 e2 partition -> LDS; A frags -> regs (verified
    // pattern: lane holds X[row = w*32 + i*16 + l15][k = s*32 + q4*8 .. +8]).
    // The one-time __syncthreads drains these loads so the main loop's vmcnt
    // queue contains ONLY stage loads (counted waits stay exact).
    for (int i4 = tid; i4 < (npart >> 3); i4 += 256)
        ((uint4*)e2s16)[i4] = ((const uint4*)e2hp)[i4];
    bf8 A[2][8];
    if (active) {
        const float* xw = xbase + (size_t)(w * 32 + l15) * D + q4 * 8;
#pragma unroll
        for (int i = 0; i < 2; ++i)
#pragma unroll
            for (int s = 0; s < 8; ++s) {
                const float* p = xw + i * 16 * D + s * 32;
                float4 a = *(const float4*)p;
                float4 b = *(const float4*)(p + 4);
                uint4 o;
                o.x = f2bf(a.x) | (f2bf(a.y) << 16);
                o.y = f2bf(a.z) | (f2bf(a.w) << 16);
                o.z = f2bf(b.x) | (f2bf(b.y) << 16);
                o.w = f2bf(b.z) | (f2bf(b.w) << 16);
                A[i][s] = *(bf8*)&o;
            }
    }
    __syncthreads();   // e2 visible; A/e2 loads drained

    // e2 rotation regs for chunk 0 (LDS u16 -> biased float)
    float e2c0 = (float)e2s16[l15] * 0.03125f;
    float e2c1 = (float)e2s16[16 + l15] * 0.03125f;

    // depth-2 prefetch: chunks 0,1 into ring 0,1
    STAGE(0, 0)
    STAGE(1, 1)

    // ---- main loop: one RAW barrier per 32-emb chunk, counted vmcnt.
    // At iter c the queue holds (oldest-first) chunks c, c+1 (4 loads each);
    // vmcnt(4) retires exactly chunk c. STAGE(c+2) reuses the ring slot last
    // read at iter c-1 — all waves passed that compute before this barrier.
#pragma unroll 1
    for (int c = 0; c < nch; ++c) {
        const int rem = nch - 1 - c;
        if (rem >= 1) asm volatile("s_waitcnt vmcnt(4)" ::: "memory");
        else          asm volatile("s_waitcnt vmcnt(0)" ::: "memory");
        __builtin_amdgcn_s_barrier();
        asm volatile("" ::: "memory");
        if (c + 2 < nch) STAGE(c + 2, (c + 2) % 3)
        if (active) {
            // prefetch next chunk's e2 pair (consumed next iteration; the
            // ds_read latency hides under this chunk's MFMAs)
            float e2n0 = 0.f, e2n1 = 0.f;
            if (c + 1 < nch) {
                e2n0 = (float)e2s16[(c + 1) * 32 + l15] * 0.03125f;
                e2n1 = (float)e2s16[(c + 1) * 32 + 16 + l15] * 0.03125f;
            }
            const char* bb = (const char*)sm + (c % 3) * 16384;
            f32x4 acc[2][2];
#pragma unroll
            for (int i = 0; i < 2; ++i)
#pragma unroll
                for (int j = 0; j < 2; ++j) acc[i][j] = (f32x4){0.f, 0.f, 0.f, 0.f};
            __builtin_amdgcn_s_setprio(1);
#pragma unroll
            for (int s = 0; s < 8; ++s) {
                const char* ba = bb + lrow + (rq ^ (unsigned)(s << 6));
                bf8 bv0 = *(const bf8*)(ba);
                bf8 bv1 = *(const bf8*)(ba + 8192);
                acc[0][0] = __builtin_amdgcn_mfma_f32_16x16x32_bf16(A[0][s], bv0, acc[0][0], 0, 0, 0);
                acc[1][0] = __builtin_amdgcn_mfma_f32_16x16x32_bf16(A[1][s], bv0, acc[1][0], 0, 0, 0);
                acc[0][1] = __builtin_amdgcn_mfma_f32_16x16x32_bf16(A[0][s], bv1, acc[0][1], 0, 0, 0);
                acc[1][1] = __builtin_amdgcn_mfma_f32_16x16x32_bf16(A[1][s], bv1, acc[1][1], 0, 0, 0);
            }
            __builtin_amdgcn_s_setprio(0);
            // fold chunk scores into per-lane packed top-3.
            // 6 ops/score: fmaf, and_or pack (positive-monotone bits, bias
            // guarantees sc>0), min/med3/max/min. 11-bit idx, 21-bit score.
#pragma unroll
            for (int j = 0; j < 2; ++j) {
                const float e2v = j ? e2c1 : e2c0;
                const unsigned elb = (unsigned)(c * 32 + j * 16 + l15);
#pragma unroll
                for (int i = 0; i < 2; ++i)
#pragma unroll
                    for (int r = 0; r < 4; ++r) {
                        float sc = fmaf(-2.f, acc[i][j][r], e2v);
                        unsigned u = __float_as_uint(sc);
                        unsigned p = (u & 0xFFFFF800u) | elb;
                        unsigned* b = t3[i][r];
                        unsigned n0 = p < b[0] ? p : b[0];
                        unsigned n1; MED3U(n1, p, b[0], b[1]);
                        unsigned x1 = p > b[1] ? p : b[1];
                        unsigned n2 = x1 < b[2] ? x1 : b[2];
                        b[0] = n0; b[1] = n1; b[2] = n2;
                    }
            }
            e2c0 = e2n0; e2c1 = e2n1;
        }
    }
    __syncthreads();   // all reads done; vmcnt already 0 — safe to overlay

    // ---- dump per-lane packed top-3 -> LDS overlay (stride 49 u32)
    unsigned* dump = (unsigned*)sm;            // [128][49]
    int* topix = (int*)sm + 128 * 49;          // [128][8]
    if (active) {
#pragma unroll
        for (int i = 0; i < 2; ++i)
#pragma unroll
            for (int r = 0; r < 4; ++r) {
                int row = w * 32 + i * 16 + q4 * 4 + r;  // C layout: row=q4*4+reg
#pragma unroll
                for (int s3 = 0; s3 < 3; ++s3)
                    dump[row * 49 + l15 * 3 + s3] = t3[i][r][s3];
            }
    }
    __syncthreads();

    // ---- per-row merge: 16 lanes x top-3 (48 cands) -> coarse top-8
    if (tid < nrows_blk) {
        unsigned h[8];
#pragma unroll
        for (int q = 0; q < 8; ++q) h[q] = 0xFFFFFFFFu;
        const unsigned* src = dump + tid * 49;
        for (int t = 0; t < 48; ++t) ins8(src[t], h);
#pragma unroll
        for (int q = 0; q < 8; ++q) topix[tid * 8 + q] = (int)(h[q] & 0x7FFu);
    }
    __syncthreads();

    // ---- exact fp32 rescore (bit-identical chain to R3..R16: single acc,
    // ascending k, score = fmaf(-2, acc, e2)) -> partition candidate lists
    float* base = out + OUT_QBASE;
    int* ibase = (int*)base;
    const int nit = nrows_blk >> 5;
    for (int it = 0; it < nit; ++it) {
        int rloc = it * 32 + (tid >> 3), cand = tid & 7;
        int el = topix[rloc * 8 + cand];
        int eg = eoff + el;
        const float* xp = xbase + (size_t)rloc * D;
        const float* ep = cb + (size_t)eg * D;
        float acc1 = 0.f;
#pragma unroll 4
        for (int qq = 0; qq < 64; ++qq) {
            float4 x = *(const float4*)(xp + qq * 4);
            float4 ee = *(const float4*)(ep + qq * 4);
            acc1 = fmaf(x.x, ee.x, acc1);
            acc1 = fmaf(x.y, ee.y, acc1);
            acc1 = fmaf(x.z, ee.z, acc1);
            acc1 = fmaf(x.w, ee.w, acc1);
        }
        float sc = fmaf(-2.f, acc1, e2full[eg]);
        if (is_class) {
            int p = blk - 512;
            base [C_SC + ((size_t)rloc * 4 + p) * 8 + cand] = sc;
            ibase[C_IX + ((size_t)rloc * 4 + p) * 8 + cand] = eg;
        } else {
            int rb = blk >> 2, pt = blk & 3;
            size_t gr = (size_t)rb * 128 + rloc;
            base [F_SC + (gr * 4 + pt) * 8 + cand] = sc;
            ibase[F_IX + (gr * 4 + pt) * 8 + cand] = eg;
        }
    }
#undef STAGE
}

// ---- final merge across the 4 partitions: exact top-3, indices + counts
// (separate kernel: must complete before vq_gather overwrites scratch)
__global__ __launch_bounds__(256)
void vq_fmerge(float* __restrict__ out, int* __restrict__ counts_f,
               int* __restrict__ counts_c)
{
    const int tid = threadIdx.x, blk = blockIdx.x;
    const float* base = out + OUT_QBASE;
    const int* ibase = (const int*)base;
    if (blk < 64) {
        size_t r = (size_t)blk * 256 + tid;   // feature row
        float fb[3] = {1e30f, 1e30f, 1e30f};
        int   fi[3] = {0x7FFFFFFF, 0x7FFFFFFF, 0x7FFFFFFF};
        for (int t = 0; t < 32; ++t)
            insert3(base[F_SC + r * 32 + t], ibase[F_IX + r * 32 + t], fb, fi);
#pragma unroll
        for (int s = 0; s < 3; ++s) {
            out[OUT_IDXBASE + (64 + r) * 3 + s] = (float)(fi[s] + NEC);
            atomicAdd(&counts_f[fi[s]], 1);
        }
    } else if (tid < 64) {
        size_t r = (size_t)tid;               // class row
        float fb[3] = {1e30f, 1e30f, 1e30f};
        int   fi[3] = {0x7FFFFFFF, 0x7FFFFFFF, 0x7FFFFFFF};
        for (int t = 0; t < 32; ++t)
            insert3(base[C_SC + r * 32 + t], ibase[C_IX + r * 32 + t], fb, fi);
#pragma unroll
        for (int s = 0; s < 3; ++s) {
            out[OUT_IDXBASE + r * 3 + s] = (float)fi[s];
            atomicAdd(&counts_c[fi[s]], 1);
        }
    }
}

// ---- gather emb[idx] -> quantized output + losses. One block per 64 rows
// (257 blocks; block 0 = class rows). Indices read back from OUT_IDXBASE.
__global__ __launch_bounds__(256)
void vq_gather(const float* __restrict__ features, const float* __restrict__ femb,
               const float* __restrict__ cemb, float* __restrict__ out,
               float* __restrict__ loss)
{
    __shared__ int sidx[192];
    __shared__ float red[256];
    const int tid = threadIdx.x, b = blockIdx.x;
    if (tid < 192) sidx[tid] = (int)out[OUT_IDXBASE + (size_t)b * 192 + tid];
    __syncthreads();
    const float* xb = features + (size_t)b * 64 * D;
    float lsum = 0.f;
    const int g = tid >> 4, l16 = tid & 15;
    for (int rs = g; rs < 192; rs += 16) {
        int rloc = rs / 3, slot = rs - rloc * 3;
        int idx = sidx[rs];
        const float* ep = (b == 0) ? cemb + (size_t)idx * D
                                   : femb + (size_t)(idx - NEC) * D;
        const float* xp = xb + (size_t)rloc * D;
        size_t ob = OUT_QBASE + (((size_t)b * 64 + rloc) * 3 + slot) * D;
#pragma unroll
        for (int qq = 0; qq < 4; ++qq) {
            int kk = (qq * 16 + l16) * 4;
            float4 e = *(const float4*)(ep + kk);
            float4 x = *(const float4*)(xp + kk);
            float dx = e.x - x.x, dy = e.y - x.y, dz = e.z - x.z, dw = e.w - x.w;
            lsum += dx * dx + dy * dy + dz * dz + dw * dw;
            // scalar stores: quantized region starts at out+1 (4B-aligned only)
            out[ob + kk + 0] = e.x; out[ob + kk + 1] = e.y;
            out[ob + kk + 2] = e.z; out[ob + kk + 3] = e.w;
        }
    }
    red[tid] = lsum;
    __syncthreads();
    for (int st = 128; st > 0; st >>= 1) {
        if (tid < st) red[tid] += red[tid + st];
        __syncthreads();
    }
    if (tid == 0) atomicAdd(b == 0 ? loss + 0 : loss + 1, red[0]);
}

// ---- scalar epilogue: perplexities + loss
__global__ __launch_bounds__(256)
void vq_finalize(float* __restrict__ out, const int* __restrict__ counts_f,
                 const int* __restrict__ counts_c, const float* __restrict__ loss)
{
    __shared__ double dred[256];
    const int tid = threadIdx.x;
    double acc = 0.0;
    for (int i = tid; i < NEF; i += 256) {
        double p = (double)counts_f[i] / 16384.0;
        acc += p * log(p + 1e-10);
    }
    dred[tid] = acc;
    __syncthreads();
    for (int st = 128; st > 0; st >>= 1) {
        if (tid < st) dred[tid] += dred[tid + st];
        __syncthreads();
    }
    double ent_f = -dred[0];
    __syncthreads();
    acc = 0.0;
    for (int i = tid; i < NEC; i += 256) {
        double p = (double)counts_c[i] / 64.0;
        acc += p * log(p + 1e-10);
    }
    dred[tid] = acc;
    __syncthreads();
    for (int st = 128; st > 0; st >>= 1) {
        if (tid < st) dred[tid] += dred[tid + st];
        __syncthreads();
    }
    double ent_c = -dred[0];
    if (tid == 0) {
        out[OUT_FPERP] = (float)exp(ent_f);
        out[OUT_CPERP] = (float)exp(ent_c);
        out[0] = 1.25f * (loss[0] / 49152.0f + loss[1] / 12582912.0f);
    }
}

extern "C" void kernel_launch(void* const* d_in, const int* in_sizes, int n_in,
                              void* d_out, int out_size, void* d_ws, size_t ws_size,
                              hipStream_t stream)
{
    const float* features = (const float*)d_in[0];  // [257*64, 256]
    const float* cemb     = (const float*)d_in[1];  // [1024, 256]
    const float* femb     = (const float*)d_in[2];  // [8192, 256]
    float* out = (float*)d_out;
    char*  ws  = (char*)d_ws;

    int*   counts_f = (int*)  (ws + WS_CNTF);
    int*   counts_c = (int*)  (ws + WS_CNTC);
    float* loss     = (float*)(ws + WS_LOSS);
    float* e2f      = (float*)(ws + WS_E2F);
    float* e2c      = (float*)(ws + WS_E2C);

    unsigned short* ebf_f = (unsigned short*)(out + OUT_QBASE + EBF_F);
    unsigned short* ebf_c = (unsigned short*)(out + OUT_QBASE + EBF_C);
    unsigned short* e2h_f = (unsigned short*)(out + OUT_QBASE + E2HF);
    unsigned short* e2h_c = (unsigned short*)(out + OUT_QBASE + E2HC);

    vq_prep<<<2304, 256, 0, stream>>>(femb, cemb, ebf_f, ebf_c, e2f, e2c,
                                      e2h_f, e2h_c, counts_f, counts_c, loss);
    vq_coarse<<<516, 256, 0, stream>>>(features, ebf_f, ebf_c, femb, cemb,
                                       e2f, e2c, e2h_f, e2h_c, out);
    vq_fmerge<<<65, 256, 0, stream>>>(out, counts_f, counts_c);
    vq_gather<<<257, 256, 0, stream>>>(features, femb, cemb, out, loss);
    vq_finalize<<<1, 256, 0, stream>>>(out, counts_f, counts_c, loss);
}

// Round 17
// 220.543 us; speedup vs baseline: 1.4417x; 1.0096x over previous
//
#include <hip/hip_runtime.h>
#include <math.h>

// Problem dims
#define D 256
#define NEF 8192        // feature codebook
#define NEC 1024        // class codebook

// Output layout (flat float32): loss | quantized[257*64*3*256] | f_perp | c_perp | idx[257*64*3]
#define OUT_QBASE   1
#define OUT_FPERP   12632065
#define OUT_CPERP   12632066
#define OUT_IDXBASE 12632067

// Scratch inside the quantized output region (rewritten by vq_gather later;
// fmerge completes before gather launches -> no overlap race). Float offsets
// (R9/R12-verified 4-partition layout):
#define F_SC  0           // feature rescored scores [16384 row][4 part][8]
#define F_IX  524288      // feature candidate codebook idx (int view)
#define C_SC  1048576     // class   rescored scores [64 row][4 part][8]
#define C_IX  1050624
#define E2HF  1052679     // u16 biased e2 of feature codebook, 4096 float slots
#define E2HC  1056775     // u16 biased e2 of class codebook (E2HF + 4096)
#define EBF_F 1064963     // bf16 feature codebook, row-major (byte addr %16==0)
#define EBF_C 2113539     // bf16 class codebook

// Workspace layout (bytes)
#define WS_CNTF  0        // 8192 int
#define WS_CNTC  32768    // 1024 int
#define WS_LOSS  36864    // float[2]: loss_c, loss_f
#define WS_E2F   49152    // 8192 float
#define WS_E2C   81920    // 1024 float

typedef short bf8 __attribute__((ext_vector_type(8)));     // 8 bf16 (4 VGPRs)
typedef float f32x4 __attribute__((ext_vector_type(4)));   // MFMA C/D frag

// float -> bf16 bits, round-to-nearest-even (coarse pass only)
__device__ __forceinline__ unsigned f2bf(float f) {
    union { float f; unsigned u; } v; v.f = f;
    return (v.u + 0x7FFFu + ((v.u >> 16) & 1u)) >> 16;
}

// async global(16B/lane) -> LDS (linear, wave-uniform base + lane*16)
__device__ __forceinline__ void gload_lds16(const void* g, void* l) {
    __builtin_amdgcn_global_load_lds(
        (const __attribute__((address_space(1))) void*)g,
        (__attribute__((address_space(3))) void*)l, 16, 0, 0);
}

// single-instruction u32 median-of-3 (gfx9+ V_MED3_U32)
#define MED3U(d, a, b_, c_) \
    asm("v_med3_u32 %0, %1, %2, %3" : "=v"(d) : "v"(a), "v"(b_), "v"(c_))

// Lexicographic (score, idx) insert — EXACT-path only (fmerge). Matches
// jax.lax.top_k stable tie-breaking.
__device__ __forceinline__ void insert3(float s, int idx, float* bs, int* bi) {
    bool lt2 = (s < bs[2]) || (s == bs[2] && idx < bi[2]);
    if (lt2) {
        bool lt1 = (s < bs[1]) || (s == bs[1] && idx < bi[1]);
        if (lt1) {
            bs[2] = bs[1]; bi[2] = bi[1];
            bool lt0 = (s < bs[0]) || (s == bs[0] && idx < bi[0]);
            if (lt0) { bs[1] = bs[0]; bi[1] = bi[0]; bs[0] = s; bi[0] = idx; }
            else     { bs[1] = s;     bi[1] = idx; }
        } else       { bs[2] = s;     bi[2] = idx; }
    }
}

// Coarse packed-u32 top-8 insert (merge phase)
__device__ __forceinline__ void ins8(unsigned p, unsigned* h) {
    if (p < h[7]) {
        h[7] = p;
#pragma unroll
        for (int q = 7; q > 0; --q)
            if (h[q] < h[q - 1]) { unsigned t = h[q]; h[q] = h[q - 1]; h[q - 1] = t; }
    }
}

// ---- fused: codebook norms + fp32->bf16 convert + workspace zeroing.
// Also emits u16 fixed-point biased norms (e2+1024)*32 for the coarse pass
// (error <= 0.016, 8x finer than the 0.125 coarse pack truncation).
__global__ __launch_bounds__(256)
void vq_prep(const float* __restrict__ femb, const float* __restrict__ cemb,
             unsigned short* __restrict__ ebf_f, unsigned short* __restrict__ ebf_c,
             float* __restrict__ e2f, float* __restrict__ e2c,
             unsigned short* __restrict__ e2h_f, unsigned short* __restrict__ e2h_c,
             int* __restrict__ counts_f, int* __restrict__ counts_c,
             float* __restrict__ loss)
{
    int zid = blockIdx.x * 256 + threadIdx.x;
    if (zid < 8192)      counts_f[zid] = 0;
    else if (zid < 9216) counts_c[zid - 8192] = 0;
    else if (zid < 9218) loss[zid - 9216] = 0.f;

    int wave = blockIdx.x * 4 + (threadIdx.x >> 6);
    int lane = threadIdx.x & 63;
    const float* src; unsigned short* dst; float* ndst; unsigned short* nh;
    if (wave < NEF) { src = femb + (size_t)wave * D; dst = ebf_f + (size_t)wave * D; ndst = e2f + wave; nh = e2h_f + wave; }
    else { int w2 = wave - NEF; src = cemb + (size_t)w2 * D; dst = ebf_c + (size_t)w2 * D; ndst = e2c + w2; nh = e2h_c + w2; }
    float4 v = *(const float4*)(src + lane * 4);
    uint2 o;
    o.x = f2bf(v.x) | (f2bf(v.y) << 16);
    o.y = f2bf(v.z) | (f2bf(v.w) << 16);
    *(uint2*)(dst + lane * 4) = o;
    float s = v.x * v.x + v.y * v.y + v.z * v.z + v.w * v.w;
#pragma unroll
    for (int off = 32; off > 0; off >>= 1) s += __shfl_down(s, off);
    if (lane == 0) {
        *ndst = s;
        *nh = (unsigned short)__float2int_rn((s + 1024.f) * 32.f);
    }
}

// ---- coarse pass, R20 = R16 + DEFERRED FOLD. The fold of chunk c's scores
// runs during chunk c+1's MFMA phase: it depends only on the PREVIOUS
// chunk's acc registers, so the scheduler interleaves its VALU ops into the
// current MFMA/ds_read stall slots (separate pipes), and the wave no longer
// drains the MFMA chain before the barrier (acc consumed next iteration).
// Top-3 is insert-order-independent -> results bit-identical to R16 (the
// c=0 dummy fold uses FLT_MAX-biased e2; its entries are evicted by any 3
// real scores). Everything else identical to R16: 128 rows x 2048-emb
// partition (4 parts, pt=blk&3, XCD-aligned), 4 waves x 32 rows, reg-A,
// 16KB chunk ring-3 via global_load_lds w16, depth-2 prefetch, RAW
// s_barrier + counted vmcnt(4), u16-e2 in LDS, med3 fold, 52KB LDS.
__global__ __launch_bounds__(256, 2)
void vq_coarse(const float* __restrict__ features,
               const unsigned short* __restrict__ ebf_f,
               const unsigned short* __restrict__ ebf_c,
               const float* __restrict__ femb, const float* __restrict__ cemb,
               const float* __restrict__ e2f, const float* __restrict__ e2c,
               const unsigned short* __restrict__ e2h_f,
               const unsigned short* __restrict__ e2h_c,
               float* __restrict__ out)
{
    __shared__ uint4 sm[3328];   // 52KB: B ring buf0..2 [0,48KB), e2u16 [48KB,52KB)
                                 // post-loop overlay in bufs: dump[128][49] + topix[128][8]
    const int tid = threadIdx.x, lane = tid & 63, w = tid >> 6;
    const int l15 = lane & 15, q4 = lane >> 4;
    const int blk = blockIdx.x;
    const bool is_class = blk >= 512;

    const float* xbase;            // block's first row (fp32 features)
    const char* ebase8;            // partition base in bf16 codebook (bytes)
    const unsigned short* e2hp;    // partition u16 biased norms
    const float* cb; const float* e2full;
    int nch, eoff, nrows_blk, npart;
    if (is_class) {
        int p = blk - 512;
        xbase = features;                      // class rows 0..63
        eoff = p * 256; nch = 8; nrows_blk = 64; npart = 256;
        ebase8 = (const char*)(ebf_c + (size_t)eoff * D);
        e2hp = e2h_c + eoff; cb = cemb; e2full = e2c;
    } else {
        int rb = blk >> 2, pt = blk & 3;
        xbase = features + (size_t)(64 + rb * 128) * D;
        eoff = pt * 2048; nch = 64; nrows_blk = 128; npart = 2048;
        ebase8 = (const char*)(ebf_f + (size_t)eoff * D);
        e2hp = e2h_f + eoff; cb = femb; e2full = e2f;
    }

    // class blocks: only waves 0,1 carry rows (64 rows); 2,3 stage+barrier only
    const bool active = !is_class || (w < 2);

    // ---- staging constants (R7/R9-verified swizzle, 16KB chunk = 4 loads/thr).
    // LDS linear byte L = ring + tid*16 + p*4096 holds chunk byte (L ^ xv),
    // xv = ((L>>9)&7)<<4 = ((tid>>5)&7)<<4 (p*4096, ring*16384 are 0 mod 8
    // in L>>9). Reader applies the same XOR.
    const unsigned xv = ((unsigned)(tid >> 5) & 7u) << 4;
    unsigned soff[4];
#pragma unroll
    for (int p = 0; p < 4; ++p)
        soff[p] = ((unsigned)(tid * 16 + p * 4096)) ^ xv;
    char* const lwb = (char*)sm + (size_t)w * 1024;   // wave's linear LDS base

#define STAGE(C, B_) {                                                          \
    const char* cb8_ = ebase8 + (size_t)(C) * 16384;                            \
    char* lb_ = lwb + (B_) * 16384;                                             \
    _Pragma("unroll")                                                           \
    for (int p = 0; p < 4; ++p)                                                 \
        gload_lds16(cb8_ + soff[p], lb_ + p * 4096);                            \
}

    // per-lane swizzled B-frag read offset pieces: logical
    // P = (j*16+l15)*512 + s*64 + q4*16, read addr = P ^ ((l15&7)<<4)
    const unsigned rq = ((unsigned)(q4 * 16)) ^ (((unsigned)(l15 & 7)) << 4);
    const unsigned lrow = (unsigned)l15 * 512;

    unsigned short* const e2s16 = (unsigned short*)((char*)sm + 49152);  // u16 biased

    unsigned t3[2][4][3];
#pragma unroll
    for (int i = 0; i < 2; ++i)
#pragma unroll
        for (int r = 0; r < 4; ++r)
#pragma unroll
            for (int s3 = 0; s3 < 3; ++s3) t3[i][r][s3] = 0xFFFFFFFFu;

    // ---- prologue: u16 e2 partition -> LDS; A frags -> regs (verified
    // pattern: lane holds X[row = w*32 + i*16 + l15][k = s*32 + q4*8 .. +8]).
    // The one-time __syncthreads drains these loads so the main loop's vmcnt
    // queue contains ONLY stage loads (counted waits stay exact).
    for (int i4 = tid; i4 < (npart >> 3); i4 += 256)
        ((uint4*)e2s16)[i4] = ((const uint4*)e2hp)[i4];
    bf8 A[2][8];
    if (active) {
        const float* xw = xbase + (size_t)(w * 32 + l15) * D + q4 * 8;
#pragma unroll
        for (int i = 0; i < 2; ++i)
#pragma unroll
            for (int s = 0; s < 8; ++s) {
                const float* p = xw + i * 16 * D + s * 32;
                float4 a = *(const float4*)p;
                float4 b = *(const float4*)(p + 4);
                uint4 o;
                o.x = f2bf(a.x) | (f2bf(a.y) << 16);
                o.y = f2bf(a.z) | (f2bf(a.w) << 16);
                o.z = f2bf(b.x) | (f2bf(b.y) << 16);
                o.w = f2bf(b.z) | (f2bf(b.w) << 16);
                A[i][s] = *(bf8*)&o;
            }
    }
    __syncthreads();   // e2 visible; A/e2 loads drained

    // deferred-fold state: previous chunk's acc (zeros) + FLT_MAX-biased e2
    // -> c=0's dummy fold produces huge-but-finite packed scores that any 3
    // real scores evict. elbP=0 is irrelevant for dummies.
    f32x4 accP[2][2];
#pragma unroll
    for (int i = 0; i < 2; ++i)
#pragma unroll
        for (int j = 0; j < 2; ++j) accP[i][j] = (f32x4){0.f, 0.f, 0.f, 0.f};
    float e2p0 = __uint_as_float(0x7F7FFFFFu);
    float e2p1 = e2p0;
    unsigned elbP = 0;

    // depth-2 prefetch: chunks 0,1 into ring 0,1
    STAGE(0, 0)
    STAGE(1, 1)

    // ---- main loop: one RAW barrier per 32-emb chunk, counted vmcnt.
    // At iter c the queue holds (oldest-first) chunks c, c+1 (4 loads each);
    // vmcnt(4) retires exactly chunk c. STAGE(c+2) reuses the ring slot last
    // read at iter c-1 — all waves passed that compute before this barrier.
#pragma unroll 1
    for (int c = 0; c < nch; ++c) {
        const int rem = nch - 1 - c;
        if (rem >= 1) asm volatile("s_waitcnt vmcnt(4)" ::: "memory");
        else          asm volatile("s_waitcnt vmcnt(0)" ::: "memory");
        __builtin_amdgcn_s_barrier();
        asm volatile("" ::: "memory");
        if (c + 2 < nch) STAGE(c + 2, (c + 2) % 3)
        if (active) {
            // this chunk's e2 pair (consumed by NEXT iteration's fold; the
            // ds_read latency hides under this chunk's MFMAs)
            float e2c0 = (float)e2s16[c * 32 + l15] * 0.03125f;
            float e2c1 = (float)e2s16[c * 32 + 16 + l15] * 0.03125f;
            const char* bb = (const char*)sm + (c % 3) * 16384;
            f32x4 acc[2][2];
#pragma unroll
            for (int i = 0; i < 2; ++i)
#pragma unroll
                for (int j = 0; j < 2; ++j) acc[i][j] = (f32x4){0.f, 0.f, 0.f, 0.f};
            __builtin_amdgcn_s_setprio(1);
#pragma unroll
            for (int s = 0; s < 8; ++s) {
                const char* ba = bb + lrow + (rq ^ (unsigned)(s << 6));
                bf8 bv0 = *(const bf8*)(ba);
                bf8 bv1 = *(const bf8*)(ba + 8192);
                acc[0][0] = __builtin_amdgcn_mfma_f32_16x16x32_bf16(A[0][s], bv0, acc[0][0], 0, 0, 0);
                acc[1][0] = __builtin_amdgcn_mfma_f32_16x16x32_bf16(A[1][s], bv0, acc[1][0], 0, 0, 0);
                acc[0][1] = __builtin_amdgcn_mfma_f32_16x16x32_bf16(A[0][s], bv1, acc[0][1], 0, 0, 0);
                acc[1][1] = __builtin_amdgcn_mfma_f32_16x16x32_bf16(A[1][s], bv1, acc[1][1], 0, 0, 0);
            }
            __builtin_amdgcn_s_setprio(0);
            // DEFERRED fold: previous chunk's scores. Independent of this
            // chunk's MFMAs -> scheduler interleaves these VALU ops into the
            // MFMA/ds_read stall slots. 6 ops/score: fmaf, and_or pack
            // (positive-monotone bits), min/med3/max/min. 11-bit idx.
#pragma unroll
            for (int j = 0; j < 2; ++j) {
                const float e2v = j ? e2p1 : e2p0;
                const unsigned elb = elbP + (unsigned)(j * 16 + l15);
#pragma unroll
                for (int i = 0; i < 2; ++i)
#pragma unroll
                    for (int r = 0; r < 4; ++r) {
                        float sc = fmaf(-2.f, accP[i][j][r], e2v);
                        unsigned u = __float_as_uint(sc);
                        unsigned p = (u & 0xFFFFF800u) | elb;
                        unsigned* b = t3[i][r];
                        unsigned n0 = p < b[0] ? p : b[0];
                        unsigned n1; MED3U(n1, p, b[0], b[1]);
                        unsigned x1 = p > b[1] ? p : b[1];
                        unsigned n2 = x1 < b[2] ? x1 : b[2];
                        b[0] = n0; b[1] = n1; b[2] = n2;
                    }
            }
            // rotate deferred state (register renames/copies, cheap)
#pragma unroll
            for (int i = 0; i < 2; ++i)
#pragma unroll
                for (int j = 0; j < 2; ++j) accP[i][j] = acc[i][j];
            e2p0 = e2c0; e2p1 = e2c1; elbP = (unsigned)(c * 32);
        }
    }
    // epilogue: fold the final chunk's scores
    if (active) {
#pragma unroll
        for (int j = 0; j < 2; ++j) {
            const float e2v = j ? e2p1 : e2p0;
            const unsigned elb = elbP + (unsigned)(j * 16 + l15);
#pragma unroll
            for (int i = 0; i < 2; ++i)
#pragma unroll
                for (int r = 0; r < 4; ++r) {
                    float sc = fmaf(-2.f, accP[i][j][r], e2v);
                    unsigned u = __float_as_uint(sc);
                    unsigned p = (u & 0xFFFFF800u) | elb;
                    unsigned* b = t3[i][r];
                    unsigned n0 = p < b[0] ? p : b[0];
                    unsigned n1; MED3U(n1, p, b[0], b[1]);
                    unsigned x1 = p > b[1] ? p : b[1];
                    unsigned n2 = x1 < b[2] ? x1 : b[2];
                    b[0] = n0; b[1] = n1; b[2] = n2;
                }
        }
    }
    __syncthreads();   // all reads done; vmcnt already 0 — safe to overlay

    // ---- dump per-lane packed top-3 -> LDS overlay (stride 49 u32)
    unsigned* dump = (unsigned*)sm;            // [128][49]
    int* topix = (int*)sm + 128 * 49;          // [128][8]
    if (active) {
#pragma unroll
        for (int i = 0; i < 2; ++i)
#pragma unroll
            for (int r = 0; r < 4; ++r) {
                int row = w * 32 + i * 16 + q4 * 4 + r;  // C layout: row=q4*4+reg
#pragma unroll
                for (int s3 = 0; s3 < 3; ++s3)
                    dump[row * 49 + l15 * 3 + s3] = t3[i][r][s3];
            }
    }
    __syncthreads();

    // ---- per-row merge: 16 lanes x top-3 (48 cands) -> coarse top-8
    if (tid < nrows_blk) {
        unsigned h[8];
#pragma unroll
        for (int q = 0; q < 8; ++q) h[q] = 0xFFFFFFFFu;
        const unsigned* src = dump + tid * 49;
        for (int t = 0; t < 48; ++t) ins8(src[t], h);
#pragma unroll
        for (int q = 0; q < 8; ++q) topix[tid * 8 + q] = (int)(h[q] & 0x7FFu);
    }
    __syncthreads();

    // ---- exact fp32 rescore (bit-identical chain to R3..R16: single acc,
    // ascending k, score = fmaf(-2, acc, e2)) -> partition candidate lists
    float* base = out + OUT_QBASE;
    int* ibase = (int*)base;
    const int nit = nrows_blk >> 5;
    for (int it = 0; it < nit; ++it) {
        int rloc = it * 32 + (tid >> 3), cand = tid & 7;
        int el = topix[rloc * 8 + cand];
        int eg = eoff + el;
        const float* xp = xbase + (size_t)rloc * D;
        const float* ep = cb + (size_t)eg * D;
        float acc1 = 0.f;
#pragma unroll 4
        for (int qq = 0; qq < 64; ++qq) {
            float4 x = *(const float4*)(xp + qq * 4);
            float4 ee = *(const float4*)(ep + qq * 4);
            acc1 = fmaf(x.x, ee.x, acc1);
            acc1 = fmaf(x.y, ee.y, acc1);
            acc1 = fmaf(x.z, ee.z, acc1);
            acc1 = fmaf(x.w, ee.w, acc1);
        }
        float sc = fmaf(-2.f, acc1, e2full[eg]);
        if (is_class) {
            int p = blk - 512;
            base [C_SC + ((size_t)rloc * 4 + p) * 8 + cand] = sc;
            ibase[C_IX + ((size_t)rloc * 4 + p) * 8 + cand] = eg;
        } else {
            int rb = blk >> 2, pt = blk & 3;
            size_t gr = (size_t)rb * 128 + rloc;
            base [F_SC + (gr * 4 + pt) * 8 + cand] = sc;
            ibase[F_IX + (gr * 4 + pt) * 8 + cand] = eg;
        }
    }
#undef STAGE
}

// ---- final merge across the 4 partitions: exact top-3, indices + counts
// (separate kernel: must complete before vq_gather overwrites scratch)
__global__ __launch_bounds__(256)
void vq_fmerge(float* __restrict__ out, int* __restrict__ counts_f,
               int* __restrict__ counts_c)
{
    const int tid = threadIdx.x, blk = blockIdx.x;
    const float* base = out + OUT_QBASE;
    const int* ibase = (const int*)base;
    if (blk < 64) {
        size_t r = (size_t)blk * 256 + tid;   // feature row
        float fb[3] = {1e30f, 1e30f, 1e30f};
        int   fi[3] = {0x7FFFFFFF, 0x7FFFFFFF, 0x7FFFFFFF};
        for (int t = 0; t < 32; ++t)
            insert3(base[F_SC + r * 32 + t], ibase[F_IX + r * 32 + t], fb, fi);
#pragma unroll
        for (int s = 0; s < 3; ++s) {
            out[OUT_IDXBASE + (64 + r) * 3 + s] = (float)(fi[s] + NEC);
            atomicAdd(&counts_f[fi[s]], 1);
        }
    } else if (tid < 64) {
        size_t r = (size_t)tid;               // class row
        float fb[3] = {1e30f, 1e30f, 1e30f};
        int   fi[3] = {0x7FFFFFFF, 0x7FFFFFFF, 0x7FFFFFFF};
        for (int t = 0; t < 32; ++t)
            insert3(base[C_SC + r * 32 + t], ibase[C_IX + r * 32 + t], fb, fi);
#pragma unroll
        for (int s = 0; s < 3; ++s) {
            out[OUT_IDXBASE + r * 3 + s] = (float)fi[s];
            atomicAdd(&counts_c[fi[s]], 1);
        }
    }
}

// ---- gather emb[idx] -> quantized output + losses. One block per 64 rows
// (257 blocks; block 0 = class rows). Indices read back from OUT_IDXBASE.
__global__ __launch_bounds__(256)
void vq_gather(const float* __restrict__ features, const float* __restrict__ femb,
               const float* __restrict__ cemb, float* __restrict__ out,
               float* __restrict__ loss)
{
    __shared__ int sidx[192];
    __shared__ float red[256];
    const int tid = threadIdx.x, b = blockIdx.x;
    if (tid < 192) sidx[tid] = (int)out[OUT_IDXBASE + (size_t)b * 192 + tid];
    __syncthreads();
    const float* xb = features + (size_t)b * 64 * D;
    float lsum = 0.f;
    const int g = tid >> 4, l16 = tid & 15;
    for (int rs = g; rs < 192; rs += 16) {
        int rloc = rs / 3, slot = rs - rloc * 3;
        int idx = sidx[rs];
        const float* ep = (b == 0) ? cemb + (size_t)idx * D
                                   : femb + (size_t)(idx - NEC) * D;
        const float* xp = xb + (size_t)rloc * D;
        size_t ob = OUT_QBASE + (((size_t)b * 64 + rloc) * 3 + slot) * D;
#pragma unroll
        for (int qq = 0; qq < 4; ++qq) {
            int kk = (qq * 16 + l16) * 4;
            float4 e = *(const float4*)(ep + kk);
            float4 x = *(const float4*)(xp + kk);
            float dx = e.x - x.x, dy = e.y - x.y, dz = e.z - x.z, dw = e.w - x.w;
            lsum += dx * dx + dy * dy + dz * dz + dw * dw;
            // scalar stores: quantized region starts at out+1 (4B-aligned only)
            out[ob + kk + 0] = e.x; out[ob + kk + 1] = e.y;
            out[ob + kk + 2] = e.z; out[ob + kk + 3] = e.w;
        }
    }
    red[tid] = lsum;
    __syncthreads();
    for (int st = 128; st > 0; st >>= 1) {
        if (tid < st) red[tid] += red[tid + st];
        __syncthreads();
    }
    if (tid == 0) atomicAdd(b == 0 ? loss + 0 : loss + 1, red[0]);
}

// ---- scalar epilogue: perplexities + loss
__global__ __launch_bounds__(256)
void vq_finalize(float* __restrict__ out, const int* __restrict__ counts_f,
                 const int* __restrict__ counts_c, const float* __restrict__ loss)
{
    __shared__ double dred[256];
    const int tid = threadIdx.x;
    double acc = 0.0;
    for (int i = tid; i < NEF; i += 256) {
        double p = (double)counts_f[i] / 16384.0;
        acc += p * log(p + 1e-10);
    }
    dred[tid] = acc;
    __syncthreads();
    for (int st = 128; st > 0; st >>= 1) {
        if (tid < st) dred[tid] += dred[tid + st];
        __syncthreads();
    }
    double ent_f = -dred[0];
    __syncthreads();
    acc = 0.0;
    for (int i = tid; i < NEC; i += 256) {
        double p = (double)counts_c[i] / 64.0;
        acc += p * log(p + 1e-10);
    }
    dred[tid] = acc;
    __syncthreads();
    for (int st = 128; st > 0; st >>= 1) {
        if (tid < st) dred[tid] += dred[tid + st];
        __syncthreads();
    }
    double ent_c = -dred[0];
    if (tid == 0) {
        out[OUT_FPERP] = (float)exp(ent_f);
        out[OUT_CPERP] = (float)exp(ent_c);
        out[0] = 1.25f * (loss[0] / 49152.0f + loss[1] / 12582912.0f);
    }
}

extern "C" void kernel_launch(void* const* d_in, const int* in_sizes, int n_in,
                              void* d_out, int out_size, void* d_ws, size_t ws_size,
                              hipStream_t stream)
{
    const float* features = (const float*)d_in[0];  // [257*64, 256]
    const float* cemb     = (const float*)d_in[1];  // [1024, 256]
    const float* femb     = (const float*)d_in[2];  // [8192, 256]
    float* out = (float*)d_out;
    char*  ws  = (char*)d_ws;

    int*   counts_f = (int*)  (ws + WS_CNTF);
    int*   counts_c = (int*)  (ws + WS_CNTC);
    float* loss     = (float*)(ws + WS_LOSS);
    float* e2f      = (float*)(ws + WS_E2F);
    float* e2c      = (float*)(ws + WS_E2C);

    unsigned short* ebf_f = (unsigned short*)(out + OUT_QBASE + EBF_F);
    unsigned short* ebf_c = (unsigned short*)(out + OUT_QBASE + EBF_C);
    unsigned short* e2h_f = (unsigned short*)(out + OUT_QBASE + E2HF);
    unsigned short* e2h_c = (unsigned short*)(out + OUT_QBASE + E2HC);

    vq_prep<<<2304, 256, 0, stream>>>(femb, cemb, ebf_f, ebf_c, e2f, e2c,
                                      e2h_f, e2h_c, counts_f, counts_c, loss);
    vq_coarse<<<516, 256, 0, stream>>>(features, ebf_f, ebf_c, femb, cemb,
                                       e2f, e2c, e2h_f, e2h_c, out);
    vq_fmerge<<<65, 256, 0, stream>>>(out, counts_f, counts_c);
    vq_gather<<<257, 256, 0, stream>>>(features, femb, cemb, out, loss);
    vq_finalize<<<1, 256, 0, stream>>>(out, counts_f, counts_c, loss);
}